// Round 16
// baseline (346.036 us; speedup 1.0000x reference)
//
#include <hip/hip_runtime.h>
#include <hip/hip_bf16.h>

#define NN 100000
#define EE 1600000
#define DOUT 40
#define LN_EPS 1e-5f
#define NBUCK 391  // buckets of 256 dst nodes
#define TILE 4096
#define TBLK 391   // ceil(EE/TILE)
#define BCAP 8192  // per-bucket capacity (expected 4092 +- 64)

typedef __attribute__((ext_vector_type(8))) short short8;   // 8 bf16 = 4 VGPRs
typedef __attribute__((ext_vector_type(4))) float f32x4;    // MFMA acc

// ---------------------------------------------------------------- bf16 helpers (RNE pack)
__device__ __forceinline__ float blo(unsigned u) { return __uint_as_float(u << 16); }
__device__ __forceinline__ float bhi(unsigned u) { return __uint_as_float(u & 0xffff0000u); }
__device__ __forceinline__ unsigned bpack(float lo, float hi) {
    unsigned a = __float_as_uint(lo);
    unsigned b = __float_as_uint(hi);
    a = (a + 0x7fffu + ((a >> 16) & 1u)) >> 16;
    b = (b + 0x7fffu + ((b >> 16) & 1u)) & 0xffff0000u;
    return (a & 0xffffu) | b;
}

// ---------------------------------------------------------------- bucket build (+ prep in last block)
__global__ __launch_bounds__(1024, 4) void bucket_k(
        const int* __restrict__ src, const int* __restrict__ dst,
        int* __restrict__ bucketCur, unsigned* __restrict__ bE,
        const float* __restrict__ W0, const float* __restrict__ W1,
        const float* __restrict__ W2,
        const float* __restrict__ mpW0, const float* __restrict__ mpb0,
        const float* __restrict__ mpW1, const float* __restrict__ mpb1,
        uint4* __restrict__ W0pk, uint4* __restrict__ W1pk,
        uint4* __restrict__ W2pk, uint4* __restrict__ Wfpk,
        float* __restrict__ bf) {
    __shared__ int cnt[8][NBUCK];
    __shared__ int basew[8][NBUCK];
    int tid = threadIdx.x;
    if (blockIdx.x == TBLK) {
        // ---------------- prep: fuse head linears + pre-pack all weights
        float* sWf = (float*)&basew[0][0];   // 12512 B >= 64*48*4 = 12288 B
        for (int i = tid; i < 64 * 48; i += 1024) {
            int k = i / 48, n = i % 48;
            float acc = 0.f;
            if (n < DOUT) {
                for (int j = 0; j < 64; ++j) acc = fmaf(mpW0[k * 64 + j], mpW1[j * DOUT + n], acc);
            }
            sWf[i] = acc;
        }
        for (int n = tid; n < 48; n += 1024) {
            float acc = 0.f;
            if (n < DOUT) {
                acc = mpb1[n];
                for (int j = 0; j < 64; ++j) acc = fmaf(mpb0[j], mpW1[j * DOUT + n], acc);
            }
            bf[n] = acc;
        }
        for (int i = tid; i < 1024; i += 1024) {
            int lane = i & 63, ct = i >> 6;
            int q = lane >> 4, ln = lane & 15;
            int c = ct >> 2, t = ct & 3;
            int row0 = c * 32 + q * 8, col = t * 16 + ln;
            uint4 u;
            u.x = bpack(W0[(row0 + 0) * 64 + col], W0[(row0 + 1) * 64 + col]);
            u.y = bpack(W0[(row0 + 2) * 64 + col], W0[(row0 + 3) * 64 + col]);
            u.z = bpack(W0[(row0 + 4) * 64 + col], W0[(row0 + 5) * 64 + col]);
            u.w = bpack(W0[(row0 + 6) * 64 + col], W0[(row0 + 7) * 64 + col]);
            W0pk[i] = u;
        }
        for (int i = tid; i < 512; i += 1024) {
            int lane = i & 63, ct = i >> 6;
            int q = lane >> 4, ln = lane & 15;
            int c = ct >> 2, t = ct & 3;
            int row0 = c * 32 + q * 8, col = t * 16 + ln;
            uint4 u;
            u.x = bpack(W1[(row0 + 0) * 64 + col], W1[(row0 + 1) * 64 + col]);
            u.y = bpack(W1[(row0 + 2) * 64 + col], W1[(row0 + 3) * 64 + col]);
            u.z = bpack(W1[(row0 + 4) * 64 + col], W1[(row0 + 5) * 64 + col]);
            u.w = bpack(W1[(row0 + 6) * 64 + col], W1[(row0 + 7) * 64 + col]);
            W1pk[i] = u;
            uint4 v;
            v.x = bpack(W2[(row0 + 0) * 64 + col], W2[(row0 + 1) * 64 + col]);
            v.y = bpack(W2[(row0 + 2) * 64 + col], W2[(row0 + 3) * 64 + col]);
            v.z = bpack(W2[(row0 + 4) * 64 + col], W2[(row0 + 5) * 64 + col]);
            v.w = bpack(W2[(row0 + 6) * 64 + col], W2[(row0 + 7) * 64 + col]);
            W2pk[i] = v;
        }
        __syncthreads();
        for (int i = tid; i < 384; i += 1024) {
            int lane = i & 63, ct = i >> 6;   // ct in 0..5
            int q = lane >> 4, ln = lane & 15;
            int c = ct / 3, t = ct % 3;
            int row0 = c * 32 + q * 8, col = t * 16 + ln;
            uint4 u;
            u.x = bpack(sWf[(row0 + 0) * 48 + col], sWf[(row0 + 1) * 48 + col]);
            u.y = bpack(sWf[(row0 + 2) * 48 + col], sWf[(row0 + 3) * 48 + col]);
            u.z = bpack(sWf[(row0 + 4) * 48 + col], sWf[(row0 + 5) * 48 + col]);
            u.w = bpack(sWf[(row0 + 6) * 48 + col], sWf[(row0 + 7) * 48 + col]);
            Wfpk[i] = u;
        }
        return;
    }
    int hv = tid >> 7;   // 0..7, two waves share one histogram row
    for (int i = tid; i < 8 * NBUCK; i += 1024) ((int*)cnt)[i] = 0;
    __syncthreads();
    const int4* dst4 = (const int4*)dst;
    const int4* src4 = (const int4*)src;
    long i4 = (long)blockIdx.x * 1024 + tid;   // TILE/4 = 1024
    int4 dv = make_int4(-1, -1, -1, -1);
    int4 sv = make_int4(0, 0, 0, 0);
    if (i4 < EE / 4) { dv = dst4[i4]; sv = src4[i4]; }
    int d[4] = {dv.x, dv.y, dv.z, dv.w};
    int s[4] = {sv.x, sv.y, sv.z, sv.w};
#pragma unroll
    for (int i = 0; i < 4; ++i) {
        if (d[i] >= 0) atomicAdd(&cnt[hv][d[i] >> 8], 1);
    }
    __syncthreads();
    for (int b = tid; b < NBUCK; b += 1024) {
        int c[8];
        int tot = 0;
#pragma unroll
        for (int w = 0; w < 8; ++w) { c[w] = cnt[w][b]; tot += c[w]; }
        int base = tot ? atomicAdd(&bucketCur[b], tot) : 0;
        int run = b * BCAP + base;
#pragma unroll
        for (int w = 0; w < 8; ++w) { basew[w][b] = run; run += c[w]; cnt[w][b] = 0; }
    }
    __syncthreads();
#pragma unroll
    for (int i = 0; i < 4; ++i) {
        if (d[i] >= 0) {
            int b = d[i] >> 8;
            int pos = basew[hv][b] + atomicAdd(&cnt[hv][b], 1);
            bE[pos] = (unsigned)s[i] | ((unsigned)(d[i] & 255) << 24);
        }
    }
}

// ---------------------------------------------------------------- bucket -> exact CSR + degI + cursor + dinv
__global__ __launch_bounds__(1024, 4) void reorder2_k(const int* __restrict__ bucketCur,
                                                      const unsigned* __restrict__ bE,
                                                      int* __restrict__ csrSrc,
                                                      int* __restrict__ degI,
                                                      int* __restrict__ cursor,
                                                      float* __restrict__ dinv) {
    __shared__ int sScan[512];
    __shared__ int sHist[256];
    __shared__ int sPre[256];
    __shared__ int sStart[256];
    int tid = threadIdx.x;
    int b = blockIdx.x;
    if (tid < 512) sScan[tid] = (tid < NBUCK) ? bucketCur[tid] : 0;
    __syncthreads();
    for (int off = 1; off < 512; off <<= 1) {
        int t = (tid >= off && tid < 512) ? sScan[tid - off] : 0;
        __syncthreads();
        if (tid < 512) sScan[tid] += t;
        __syncthreads();
    }
    int bbase = (b == 0) ? 0 : sScan[b - 1];   // LDS broadcast
    if (tid < 256) sHist[tid] = 0;
    __syncthreads();
    int start = b * BCAP;
    int ecnt = bucketCur[b];
    int nq = ecnt >> 2;
    const uint4* bE4 = (const uint4*)(bE + start);
    for (int i = tid; i < nq; i += 1024) {
        uint4 v = bE4[i];
        atomicAdd(&sHist[v.x >> 24], 1);
        atomicAdd(&sHist[v.y >> 24], 1);
        atomicAdd(&sHist[v.z >> 24], 1);
        atomicAdd(&sHist[v.w >> 24], 1);
    }
    for (int e = (nq << 2) + tid; e < ecnt; e += 1024) {
        atomicAdd(&sHist[bE[start + e] >> 24], 1);
    }
    __syncthreads();
    if (tid < 256) sPre[tid] = sHist[tid];
    __syncthreads();
    for (int off = 1; off < 256; off <<= 1) {
        int t = (tid >= off && tid < 256) ? sPre[tid - off] : 0;
        __syncthreads();
        if (tid < 256) sPre[tid] += t;
        __syncthreads();
    }
    if (tid < 256) {
        int h = sHist[tid];
        int excl = sPre[tid] - h;
        int st = bbase + excl;
        sStart[tid] = st;
        int nd = (b << 8) + tid;
        if (nd < NN) {
            degI[nd] = h;
            cursor[nd] = st;
            dinv[nd] = rsqrtf((float)h + 1.0f);
        }
    }
    __syncthreads();
    for (int i = tid; i < nq; i += 1024) {
        uint4 v = bE4[i];
        int p0 = atomicAdd(&sStart[v.x >> 24], 1);
        csrSrc[p0] = (int)(v.x & 0xFFFFFFu);
        int p1 = atomicAdd(&sStart[v.y >> 24], 1);
        csrSrc[p1] = (int)(v.y & 0xFFFFFFu);
        int p2 = atomicAdd(&sStart[v.z >> 24], 1);
        csrSrc[p2] = (int)(v.z & 0xFFFFFFu);
        int p3 = atomicAdd(&sStart[v.w >> 24], 1);
        csrSrc[p3] = (int)(v.w & 0xFFFFFFu);
    }
    for (int e = (nq << 2) + tid; e < ecnt; e += 1024) {
        unsigned v = bE[start + e];
        int pos = atomicAdd(&sStart[v >> 24], 1);
        csrSrc[pos] = (int)(v & 0xFFFFFFu);
    }
}

// ---------------------------------------------------------------- MFMA GEMM layer 0 (f32 input): H' = bf16((X@W0)*dinv)
__global__ __launch_bounds__(256, 4) void gemm0(const float* __restrict__ X,
                                                const uint4* __restrict__ Wpk,
                                                const float* __restrict__ dinv,
                                                unsigned* __restrict__ H) {
    __shared__ float sD[64 * 65];
    int tid = threadIdx.x;
    int wv = tid >> 6, lane = tid & 63;
    int q = lane >> 4, ln = lane & 15;
    int base = blockIdx.x * 64;
    int node = base + wv * 16 + ln;
    bool ok = node < NN;
    short8 afrag[4];
#pragma unroll
    for (int c = 0; c < 4; ++c) {
        float4 f0 = make_float4(0.f, 0.f, 0.f, 0.f);
        float4 f1 = make_float4(0.f, 0.f, 0.f, 0.f);
        if (ok) {
            const float4* xp = (const float4*)(X + (long)node * 128 + c * 32 + q * 8);
            f0 = xp[0];
            f1 = xp[1];
        }
        uint4 u;
        u.x = bpack(f0.x, f0.y);
        u.y = bpack(f0.z, f0.w);
        u.z = bpack(f1.x, f1.y);
        u.w = bpack(f1.z, f1.w);
        afrag[c] = __builtin_bit_cast(short8, u);
    }
#pragma unroll
    for (int t = 0; t < 4; ++t) {
        f32x4 acc = {0.f, 0.f, 0.f, 0.f};
#pragma unroll
        for (int c = 0; c < 4; ++c) {
            short8 bfrag = __builtin_bit_cast(short8, Wpk[(c * 4 + t) * 64 + lane]);
            acc = __builtin_amdgcn_mfma_f32_16x16x32_bf16(afrag[c], bfrag, acc, 0, 0, 0);
        }
#pragma unroll
        for (int r = 0; r < 4; ++r)
            sD[(wv * 16 + q * 4 + r) * 65 + t * 16 + ln] = acc[r];
    }
    __syncthreads();
    for (int i = tid; i < 64 * 32; i += 256) {
        int row = i >> 5, c2 = i & 31;
        int nd = base + row;
        if (nd < NN) {
            float di = dinv[nd];
            float lo = sD[row * 65 + c2 * 2] * di;
            float hi = sD[row * 65 + c2 * 2 + 1] * di;
            H[nd * 32 + c2] = bpack(lo, hi);
        }
    }
}

// ---------------------------------------------------------------- fused aggregate + relu (+LN) + PER-WAVE next-layer GEMM
// 256 threads = 4 waves = 4 nodes/block (100000 = 25000*4), NO LDS, NO
// barriers (round-15's 16-node block version paid ~13.5us in staging/
// barriers).  After the shuffle-reduce every lane holds the reduced
// features, so the wave builds an MFMA A operand whose 16 rows are all
// copies of h via 16 __shfl + 8 bpack (lane 16q+m holds k-slots q*8..
// q*8+7 = feats from f=2q,2q+1 / chunk1 f=2q+8,2q+9).  D's rows are all
// h@W; row 0 lives in reg0 of lanes 0..15.  Bit-identical operands to
// the old gemm_b/mlp.  __shfl always under full exec (round-8 lesson).
template <int DOLN, int FINAL>
__global__ __launch_bounds__(256, 4) void aggf_k(
        const int* __restrict__ cursor, const int* __restrict__ degI,
        const int* __restrict__ csrSrc, const float* __restrict__ dinv,
        const uint2* __restrict__ H2, const float4* __restrict__ bias4,
        const float4* __restrict__ g4, const float4* __restrict__ beta4,
        const uint4* __restrict__ Wpk, const float* __restrict__ bfv,
        unsigned* __restrict__ Hout, float* __restrict__ outF) {
    int tid = threadIdx.x;
    int w = tid >> 6, lane = tid & 63;
    int g = lane >> 4;
    unsigned f = (unsigned)(lane & 15);
    unsigned node = (unsigned)(blockIdx.x * 4 + w);   // always < NN (exact grid)
    int start = cursor[node];
    int deg = degI[node];
    int myIdx = 0;
    if (lane < deg) myIdx = csrSrc[(unsigned)(start + lane)];
    uint2 qs = H2[node * 16u + f];
    float di = dinv[node];
    float4 bb = bias4[f];
    float ax = 0.f, ay = 0.f, az = 0.f, aw = 0.f;
    float bx = 0.f, by = 0.f, bz = 0.f, bw = 0.f;
    uint2 qa[4];
#pragma unroll
    for (int r = 0; r < 4; ++r) {
        int e = r * 4 + g;
        unsigned s = (unsigned)__shfl(myIdx, e);
        qa[r] = make_uint2(0u, 0u);
        if (e < deg) qa[r] = H2[s * 16u + f];
    }
    if (deg <= 16) {
#pragma unroll
        for (int r = 0; r < 4; r += 2) {
            ax += blo(qa[r].x);     ay += bhi(qa[r].x);
            az += blo(qa[r].y);     aw += bhi(qa[r].y);
            bx += blo(qa[r + 1].x); by += bhi(qa[r + 1].x);
            bz += blo(qa[r + 1].y); bw += bhi(qa[r + 1].y);
        }
    } else {
        uint2 qb[4];
#pragma unroll
        for (int r = 0; r < 4; ++r) {
            int e = 16 + r * 4 + g;
            unsigned s = (unsigned)__shfl(myIdx, e);
            qb[r] = make_uint2(0u, 0u);
            if (e < deg) qb[r] = H2[s * 16u + f];
        }
#pragma unroll
        for (int r = 0; r < 4; r += 2) {
            ax += blo(qa[r].x);     ay += bhi(qa[r].x);
            az += blo(qa[r].y);     aw += bhi(qa[r].y);
            bx += blo(qa[r + 1].x); by += bhi(qa[r + 1].x);
            bz += blo(qa[r + 1].y); bw += bhi(qa[r + 1].y);
        }
#pragma unroll
        for (int r = 0; r < 4; r += 2) {
            ax += blo(qb[r].x);     ay += bhi(qb[r].x);
            az += blo(qb[r].y);     aw += bhi(qb[r].y);
            bx += blo(qb[r + 1].x); by += bhi(qb[r + 1].x);
            bz += blo(qb[r + 1].y); bw += bhi(qb[r + 1].y);
        }
        if (deg > 32) {
            int R2 = (deg + 3) >> 2;
            if (R2 > 16) R2 = 16;
            for (int r = 8; r < R2; ++r) {
                int e = r * 4 + g;
                unsigned s = (unsigned)__shfl(myIdx, e);
                uint2 qq = make_uint2(0u, 0u);
                if (e < deg) qq = H2[s * 16u + f];
                ax += blo(qq.x); ay += bhi(qq.x); az += blo(qq.y); aw += bhi(qq.y);
            }
            for (int ee = 64 + g; ee < deg; ee += 4) {
                uint2 qq = H2[(unsigned)csrSrc[(unsigned)(start + ee)] * 16u + f];
                ax += blo(qq.x); ay += bhi(qq.x); az += blo(qq.y); aw += bhi(qq.y);
            }
        }
    }
    ax += bx; ay += by; az += bz; aw += bw;
    ax += __shfl_xor(ax, 16); ay += __shfl_xor(ay, 16);
    az += __shfl_xor(az, 16); aw += __shfl_xor(aw, 16);
    ax += __shfl_xor(ax, 32); ay += __shfl_xor(ay, 32);
    az += __shfl_xor(az, 32); aw += __shfl_xor(aw, 32);
    float vx = fmaxf((ax + blo(qs.x)) * di + bb.x, 0.f);
    float vy = fmaxf((ay + bhi(qs.x)) * di + bb.y, 0.f);
    float vz = fmaxf((az + blo(qs.y)) * di + bb.z, 0.f);
    float vw = fmaxf((aw + bhi(qs.y)) * di + bb.w, 0.f);
    if (DOLN) {
        float s = vx + vy + vz + vw;
        s += __shfl_xor(s, 1); s += __shfl_xor(s, 2);
        s += __shfl_xor(s, 4); s += __shfl_xor(s, 8);
        float mu = s * (1.f / 64.f);
        vx -= mu; vy -= mu; vz -= mu; vw -= mu;
        float vs = vx * vx + vy * vy + vz * vz + vw * vw;
        vs += __shfl_xor(vs, 1); vs += __shfl_xor(vs, 2);
        vs += __shfl_xor(vs, 4); vs += __shfl_xor(vs, 8);
        float inv = rsqrtf(vs * (1.f / 64.f) + LN_EPS);
        float4 gg = g4[f];
        float4 tt = beta4[f];
        vx = vx * inv * gg.x + tt.x;
        vy = vy * inv * gg.y + tt.y;
        vz = vz * inv * gg.z + tt.z;
        vw = vw * inv * gg.w + tt.w;
    }
    // ---- per-wave fused GEMM: all 16 A-rows = h (lane 16q+m holds feats
    // from f-pairs (2q,2q+1) chunk0 / (2q+8,2q+9) chunk1)
    int q2 = (lane >> 4) * 2;
    float c0x = __shfl(vx, q2),     c0y = __shfl(vy, q2);
    float c0z = __shfl(vz, q2),     c0w = __shfl(vw, q2);
    float c1x = __shfl(vx, q2 + 1), c1y = __shfl(vy, q2 + 1);
    float c1z = __shfl(vz, q2 + 1), c1w = __shfl(vw, q2 + 1);
    float c2x = __shfl(vx, q2 + 8), c2y = __shfl(vy, q2 + 8);
    float c2z = __shfl(vz, q2 + 8), c2w = __shfl(vw, q2 + 8);
    float c3x = __shfl(vx, q2 + 9), c3y = __shfl(vy, q2 + 9);
    float c3z = __shfl(vz, q2 + 9), c3w = __shfl(vw, q2 + 9);
    uint4 ua0 = make_uint4(bpack(c0x, c0y), bpack(c0z, c0w), bpack(c1x, c1y), bpack(c1z, c1w));
    uint4 ua1 = make_uint4(bpack(c2x, c2y), bpack(c2z, c2w), bpack(c3x, c3y), bpack(c3z, c3w));
    short8 a0 = __builtin_bit_cast(short8, ua0);
    short8 a1 = __builtin_bit_cast(short8, ua1);
    constexpr int NT = FINAL ? 3 : 4;
#pragma unroll
    for (int t = 0; t < NT; ++t) {
        f32x4 acc = {0.f, 0.f, 0.f, 0.f};
        acc = __builtin_amdgcn_mfma_f32_16x16x32_bf16(
            a0, __builtin_bit_cast(short8, Wpk[(0 * NT + t) * 64 + lane]), acc, 0, 0, 0);
        acc = __builtin_amdgcn_mfma_f32_16x16x32_bf16(
            a1, __builtin_bit_cast(short8, Wpk[(1 * NT + t) * 64 + lane]), acc, 0, 0, 0);
        if (FINAL) {
            int col = t * 16 + lane;       // lanes 0..15 hold row 0 in reg 0
            if (lane < 16 && col < DOUT) outF[node * (unsigned)DOUT + col] = acc[0] + bfv[col];
        } else {
            float vv = acc[0] * di;
            float lo = __shfl(vv, lane & ~1);
            float hi = __shfl(vv, (lane & ~1) | 1);
            if (lane < 16 && !(lane & 1))
                Hout[node * 32u + t * 8 + (lane >> 1)] = bpack(lo, hi);
        }
    }
}

// ----------------------------------------------------------------
extern "C" void kernel_launch(void* const* d_in, const int* in_sizes, int n_in,
                              void* d_out, int out_size, void* d_ws, size_t ws_size,
                              hipStream_t stream) {
    const float* x    = (const float*)d_in[0];
    const int*   ei   = (const int*)d_in[1];
    const int*   srcI = ei;
    const int*   dstI = ei + EE;
    const float* W0   = (const float*)d_in[2];
    const float* b0   = (const float*)d_in[3];
    const float* W1   = (const float*)d_in[4];
    const float* b1   = (const float*)d_in[5];
    const float* W2   = (const float*)d_in[6];
    const float* b2   = (const float*)d_in[7];
    const float* ln0g = (const float*)d_in[8];
    const float* ln0b = (const float*)d_in[9];
    const float* ln1g = (const float*)d_in[10];
    const float* ln1b = (const float*)d_in[11];
    const float* mpW0 = (const float*)d_in[12];
    const float* mpb0 = (const float*)d_in[13];
    const float* mpW1 = (const float*)d_in[14];
    const float* mpb1 = (const float*)d_in[15];
    float* out = (float*)d_out;

    char* ws = (char*)d_ws;
    float*    dinv      = (float*)   (ws + 0);                      // 400 KB
    int*      degI      = (int*)     (ws + 512l * 1024);            // 400 KB
    int*      cursor    = (int*)     (ws + 1024l * 1024);           // 400 KB
    int*      bucketCur = (int*)     (ws + 1600l * 1024);
    uint4*    W0pk      = (uint4*)   (ws + 1792l * 1024);           // 16 KB
    uint4*    W1pk      = (uint4*)   (ws + 1824l * 1024);           // 8 KB
    uint4*    W2pk      = (uint4*)   (ws + 1856l * 1024);           // 8 KB
    uint4*    Wfpk      = (uint4*)   (ws + 1888l * 1024);           // 6 KB
    float*    bfv       = (float*)   (ws + 1920l * 1024);           // 192 B
    unsigned* bE        = (unsigned*)(ws + 2048l * 1024);           // 391*8192*4 = 12.8 MB
    int*      csrSrc    = (int*)     (ws + 15l * 1024 * 1024);      // 6.4 MB
    unsigned* bufA      = (unsigned*)(ws + 22l * 1024 * 1024);      // bf16 H' 12.8 MB
    unsigned* bufB      = (unsigned*)(ws + 36l * 1024 * 1024);      // bf16 H' ping-pong 12.8 MB

    const int aggBlocks  = NN / 4;             // 25000 exact
    const int gemmBlocks = (NN + 63) / 64;     // 1563

    hipMemsetAsync(bucketCur, 0, NBUCK * sizeof(int), stream);
    bucket_k<<<TBLK + 1, 1024, 0, stream>>>(srcI, dstI, bucketCur, bE,
                                            W0, W1, W2, mpW0, mpb0, mpW1, mpb1,
                                            W0pk, W1pk, W2pk, Wfpk, bfv);
    reorder2_k<<<NBUCK, 1024, 0, stream>>>(bucketCur, bE, csrSrc, degI, cursor, dinv);

    // layer 0 GEMM (f32 input)
    gemm0<<<gemmBlocks, 256, 0, stream>>>(x, W0pk, dinv, bufA);
    // conv0 finish (LN0) + fused GEMM W1
    aggf_k<1, 0><<<aggBlocks, 256, 0, stream>>>(cursor, degI, csrSrc, dinv,
                                                (const uint2*)bufA, (const float4*)b0,
                                                (const float4*)ln0g, (const float4*)ln0b,
                                                W1pk, bfv, bufB, out);
    // conv1 finish (LN1) + fused GEMM W2
    aggf_k<1, 0><<<aggBlocks, 256, 0, stream>>>(cursor, degI, csrSrc, dinv,
                                                (const uint2*)bufB, (const float4*)b1,
                                                (const float4*)ln1g, (const float4*)ln1b,
                                                W2pk, bfv, bufA, out);
    // conv2 finish (no LN) + fused head GEMM Wf + bf -> output
    aggf_k<0, 1><<<aggBlocks, 256, 0, stream>>>(cursor, degI, csrSrc, dinv,
                                                (const uint2*)bufA, (const float4*)b2,
                                                (const float4*)ln0g, (const float4*)ln0b,
                                                Wfpk, bfv, bufB, out);
}

// Round 17
// 322.325 us; speedup vs baseline: 1.0736x; 1.0736x over previous
//
#include <hip/hip_runtime.h>
#include <hip/hip_bf16.h>

#define NN 100000
#define EE 1600000
#define DOUT 40
#define LN_EPS 1e-5f
#define NBUCK 391  // buckets of 256 dst nodes
#define TILE 4096
#define TBLK 391   // ceil(EE/TILE)
#define BCAP 8192  // per-bucket capacity (expected 4092 +- 64)

typedef __attribute__((ext_vector_type(8))) short short8;   // 8 bf16 = 4 VGPRs
typedef __attribute__((ext_vector_type(4))) float f32x4;    // MFMA acc

// ---------------------------------------------------------------- bf16 helpers (RNE pack)
__device__ __forceinline__ float blo(unsigned u) { return __uint_as_float(u << 16); }
__device__ __forceinline__ float bhi(unsigned u) { return __uint_as_float(u & 0xffff0000u); }
__device__ __forceinline__ unsigned bpack(float lo, float hi) {
    unsigned a = __float_as_uint(lo);
    unsigned b = __float_as_uint(hi);
    a = (a + 0x7fffu + ((a >> 16) & 1u)) >> 16;
    b = (b + 0x7fffu + ((b >> 16) & 1u)) & 0xffff0000u;
    return (a & 0xffffu) | b;
}

// ---------------------------------------------------------------- bucket build (+ prep in last block)
__global__ __launch_bounds__(1024, 4) void bucket_k(
        const int* __restrict__ src, const int* __restrict__ dst,
        int* __restrict__ bucketCur, unsigned* __restrict__ bE,
        const float* __restrict__ W0, const float* __restrict__ W1,
        const float* __restrict__ W2,
        const float* __restrict__ mpW0, const float* __restrict__ mpb0,
        const float* __restrict__ mpW1, const float* __restrict__ mpb1,
        uint4* __restrict__ W0pk, uint4* __restrict__ W1pk,
        uint4* __restrict__ W2pk, uint4* __restrict__ Wfpk,
        float* __restrict__ bf) {
    __shared__ int cnt[8][NBUCK];
    __shared__ int basew[8][NBUCK];
    int tid = threadIdx.x;
    if (blockIdx.x == TBLK) {
        // ---------------- prep: fuse head linears + pre-pack all weights
        float* sWf = (float*)&basew[0][0];   // 12512 B >= 64*48*4 = 12288 B
        for (int i = tid; i < 64 * 48; i += 1024) {
            int k = i / 48, n = i % 48;
            float acc = 0.f;
            if (n < DOUT) {
                for (int j = 0; j < 64; ++j) acc = fmaf(mpW0[k * 64 + j], mpW1[j * DOUT + n], acc);
            }
            sWf[i] = acc;
        }
        for (int n = tid; n < 48; n += 1024) {
            float acc = 0.f;
            if (n < DOUT) {
                acc = mpb1[n];
                for (int j = 0; j < 64; ++j) acc = fmaf(mpb0[j], mpW1[j * DOUT + n], acc);
            }
            bf[n] = acc;
        }
        for (int i = tid; i < 1024; i += 1024) {
            int lane = i & 63, ct = i >> 6;
            int q = lane >> 4, ln = lane & 15;
            int c = ct >> 2, t = ct & 3;
            int row0 = c * 32 + q * 8, col = t * 16 + ln;
            uint4 u;
            u.x = bpack(W0[(row0 + 0) * 64 + col], W0[(row0 + 1) * 64 + col]);
            u.y = bpack(W0[(row0 + 2) * 64 + col], W0[(row0 + 3) * 64 + col]);
            u.z = bpack(W0[(row0 + 4) * 64 + col], W0[(row0 + 5) * 64 + col]);
            u.w = bpack(W0[(row0 + 6) * 64 + col], W0[(row0 + 7) * 64 + col]);
            W0pk[i] = u;
        }
        for (int i = tid; i < 512; i += 1024) {
            int lane = i & 63, ct = i >> 6;
            int q = lane >> 4, ln = lane & 15;
            int c = ct >> 2, t = ct & 3;
            int row0 = c * 32 + q * 8, col = t * 16 + ln;
            uint4 u;
            u.x = bpack(W1[(row0 + 0) * 64 + col], W1[(row0 + 1) * 64 + col]);
            u.y = bpack(W1[(row0 + 2) * 64 + col], W1[(row0 + 3) * 64 + col]);
            u.z = bpack(W1[(row0 + 4) * 64 + col], W1[(row0 + 5) * 64 + col]);
            u.w = bpack(W1[(row0 + 6) * 64 + col], W1[(row0 + 7) * 64 + col]);
            W1pk[i] = u;
            uint4 v;
            v.x = bpack(W2[(row0 + 0) * 64 + col], W2[(row0 + 1) * 64 + col]);
            v.y = bpack(W2[(row0 + 2) * 64 + col], W2[(row0 + 3) * 64 + col]);
            v.z = bpack(W2[(row0 + 4) * 64 + col], W2[(row0 + 5) * 64 + col]);
            v.w = bpack(W2[(row0 + 6) * 64 + col], W2[(row0 + 7) * 64 + col]);
            W2pk[i] = v;
        }
        __syncthreads();
        for (int i = tid; i < 384; i += 1024) {
            int lane = i & 63, ct = i >> 6;   // ct in 0..5
            int q = lane >> 4, ln = lane & 15;
            int c = ct / 3, t = ct % 3;
            int row0 = c * 32 + q * 8, col = t * 16 + ln;
            uint4 u;
            u.x = bpack(sWf[(row0 + 0) * 48 + col], sWf[(row0 + 1) * 48 + col]);
            u.y = bpack(sWf[(row0 + 2) * 48 + col], sWf[(row0 + 3) * 48 + col]);
            u.z = bpack(sWf[(row0 + 4) * 48 + col], sWf[(row0 + 5) * 48 + col]);
            u.w = bpack(sWf[(row0 + 6) * 48 + col], sWf[(row0 + 7) * 48 + col]);
            Wfpk[i] = u;
        }
        return;
    }
    int hv = tid >> 7;   // 0..7, two waves share one histogram row
    for (int i = tid; i < 8 * NBUCK; i += 1024) ((int*)cnt)[i] = 0;
    __syncthreads();
    const int4* dst4 = (const int4*)dst;
    const int4* src4 = (const int4*)src;
    long i4 = (long)blockIdx.x * 1024 + tid;   // TILE/4 = 1024
    int4 dv = make_int4(-1, -1, -1, -1);
    int4 sv = make_int4(0, 0, 0, 0);
    if (i4 < EE / 4) { dv = dst4[i4]; sv = src4[i4]; }
    int d[4] = {dv.x, dv.y, dv.z, dv.w};
    int s[4] = {sv.x, sv.y, sv.z, sv.w};
#pragma unroll
    for (int i = 0; i < 4; ++i) {
        if (d[i] >= 0) atomicAdd(&cnt[hv][d[i] >> 8], 1);
    }
    __syncthreads();
    for (int b = tid; b < NBUCK; b += 1024) {
        int c[8];
        int tot = 0;
#pragma unroll
        for (int w = 0; w < 8; ++w) { c[w] = cnt[w][b]; tot += c[w]; }
        int base = tot ? atomicAdd(&bucketCur[b], tot) : 0;
        int run = b * BCAP + base;
#pragma unroll
        for (int w = 0; w < 8; ++w) { basew[w][b] = run; run += c[w]; cnt[w][b] = 0; }
    }
    __syncthreads();
#pragma unroll
    for (int i = 0; i < 4; ++i) {
        if (d[i] >= 0) {
            int b = d[i] >> 8;
            int pos = basew[hv][b] + atomicAdd(&cnt[hv][b], 1);
            bE[pos] = (unsigned)s[i] | ((unsigned)(d[i] & 255) << 24);
        }
    }
}

// ---------------------------------------------------------------- bucket -> exact CSR + degI + cursor + dinv
__global__ __launch_bounds__(1024, 4) void reorder2_k(const int* __restrict__ bucketCur,
                                                      const unsigned* __restrict__ bE,
                                                      int* __restrict__ csrSrc,
                                                      int* __restrict__ degI,
                                                      int* __restrict__ cursor,
                                                      float* __restrict__ dinv) {
    __shared__ int sScan[512];
    __shared__ int sHist[256];
    __shared__ int sPre[256];
    __shared__ int sStart[256];
    int tid = threadIdx.x;
    int b = blockIdx.x;
    if (tid < 512) sScan[tid] = (tid < NBUCK) ? bucketCur[tid] : 0;
    __syncthreads();
    for (int off = 1; off < 512; off <<= 1) {
        int t = (tid >= off && tid < 512) ? sScan[tid - off] : 0;
        __syncthreads();
        if (tid < 512) sScan[tid] += t;
        __syncthreads();
    }
    int bbase = (b == 0) ? 0 : sScan[b - 1];   // LDS broadcast
    if (tid < 256) sHist[tid] = 0;
    __syncthreads();
    int start = b * BCAP;
    int ecnt = bucketCur[b];
    int nq = ecnt >> 2;
    const uint4* bE4 = (const uint4*)(bE + start);
    for (int i = tid; i < nq; i += 1024) {
        uint4 v = bE4[i];
        atomicAdd(&sHist[v.x >> 24], 1);
        atomicAdd(&sHist[v.y >> 24], 1);
        atomicAdd(&sHist[v.z >> 24], 1);
        atomicAdd(&sHist[v.w >> 24], 1);
    }
    for (int e = (nq << 2) + tid; e < ecnt; e += 1024) {
        atomicAdd(&sHist[bE[start + e] >> 24], 1);
    }
    __syncthreads();
    if (tid < 256) sPre[tid] = sHist[tid];
    __syncthreads();
    for (int off = 1; off < 256; off <<= 1) {
        int t = (tid >= off && tid < 256) ? sPre[tid - off] : 0;
        __syncthreads();
        if (tid < 256) sPre[tid] += t;
        __syncthreads();
    }
    if (tid < 256) {
        int h = sHist[tid];
        int excl = sPre[tid] - h;
        int st = bbase + excl;
        sStart[tid] = st;
        int nd = (b << 8) + tid;
        if (nd < NN) {
            degI[nd] = h;
            cursor[nd] = st;
            dinv[nd] = rsqrtf((float)h + 1.0f);
        }
    }
    __syncthreads();
    for (int i = tid; i < nq; i += 1024) {
        uint4 v = bE4[i];
        int p0 = atomicAdd(&sStart[v.x >> 24], 1);
        csrSrc[p0] = (int)(v.x & 0xFFFFFFu);
        int p1 = atomicAdd(&sStart[v.y >> 24], 1);
        csrSrc[p1] = (int)(v.y & 0xFFFFFFu);
        int p2 = atomicAdd(&sStart[v.z >> 24], 1);
        csrSrc[p2] = (int)(v.z & 0xFFFFFFu);
        int p3 = atomicAdd(&sStart[v.w >> 24], 1);
        csrSrc[p3] = (int)(v.w & 0xFFFFFFu);
    }
    for (int e = (nq << 2) + tid; e < ecnt; e += 1024) {
        unsigned v = bE[start + e];
        int pos = atomicAdd(&sStart[v >> 24], 1);
        csrSrc[pos] = (int)(v & 0xFFFFFFu);
    }
}

// ---------------------------------------------------------------- MFMA GEMM layer 0 (f32 input): H' = bf16((X@W0)*dinv)
__global__ __launch_bounds__(256, 4) void gemm0(const float* __restrict__ X,
                                                const uint4* __restrict__ Wpk,
                                                const float* __restrict__ dinv,
                                                unsigned* __restrict__ H) {
    __shared__ float sD[64 * 65];
    int tid = threadIdx.x;
    int wv = tid >> 6, lane = tid & 63;
    int q = lane >> 4, ln = lane & 15;
    int base = blockIdx.x * 64;
    int node = base + wv * 16 + ln;
    bool ok = node < NN;
    short8 afrag[4];
#pragma unroll
    for (int c = 0; c < 4; ++c) {
        float4 f0 = make_float4(0.f, 0.f, 0.f, 0.f);
        float4 f1 = make_float4(0.f, 0.f, 0.f, 0.f);
        if (ok) {
            const float4* xp = (const float4*)(X + (long)node * 128 + c * 32 + q * 8);
            f0 = xp[0];
            f1 = xp[1];
        }
        uint4 u;
        u.x = bpack(f0.x, f0.y);
        u.y = bpack(f0.z, f0.w);
        u.z = bpack(f1.x, f1.y);
        u.w = bpack(f1.z, f1.w);
        afrag[c] = __builtin_bit_cast(short8, u);
    }
#pragma unroll
    for (int t = 0; t < 4; ++t) {
        f32x4 acc = {0.f, 0.f, 0.f, 0.f};
#pragma unroll
        for (int c = 0; c < 4; ++c) {
            short8 bfrag = __builtin_bit_cast(short8, Wpk[(c * 4 + t) * 64 + lane]);
            acc = __builtin_amdgcn_mfma_f32_16x16x32_bf16(afrag[c], bfrag, acc, 0, 0, 0);
        }
#pragma unroll
        for (int r = 0; r < 4; ++r)
            sD[(wv * 16 + q * 4 + r) * 65 + t * 16 + ln] = acc[r];
    }
    __syncthreads();
    for (int i = tid; i < 64 * 32; i += 256) {
        int row = i >> 5, c2 = i & 31;
        int nd = base + row;
        if (nd < NN) {
            float di = dinv[nd];
            float lo = sD[row * 65 + c2 * 2] * di;
            float hi = sD[row * 65 + c2 * 2 + 1] * di;
            H[nd * 32 + c2] = bpack(lo, hi);
        }
    }
}

// ---------------------------------------------------------------- fused aggregate + relu (+LN) + NEXT-LAYER GEMM
// 1024 threads = 16 waves = 16 nodes/block (100000 = 6250*16 exact).
// Gather: one wave per node (round-9/10 structure, __shfl under full exec).
// Epilogue: post-LN rows staged in LDS (packed-H bit layout), ONE barrier,
// then waves 0..NT-1 run the MFMAs and write results DIRECTLY to global
// (intra-wave shfl pairs the columns for packed-bf16 output) - round-15's
// sD staging + second barrier + block-wide output loop are deleted (that
// staging was most of its +13.5us overhead; round-16's per-wave-MFMA
// variant was worse: 15/16 wasted MFMA rows + 18 shfl on the VALU path).
template <int DOLN, int FINAL>
__global__ __launch_bounds__(1024, 8) void aggf_k(
        const int* __restrict__ cursor, const int* __restrict__ degI,
        const int* __restrict__ csrSrc, const float* __restrict__ dinv,
        const uint2* __restrict__ H2, const float4* __restrict__ bias4,
        const float4* __restrict__ g4, const float4* __restrict__ beta4,
        const uint4* __restrict__ Wpk, const float* __restrict__ bfv,
        unsigned* __restrict__ Hout, float* __restrict__ outF) {
    __shared__ __align__(16) unsigned sH[16][36];  // 36-word pitch: 2-way-free banks on uint4 reads
    int tid = threadIdx.x;
    int wv = tid >> 6, lane = tid & 63;
    int g = lane >> 4;
    unsigned f = (unsigned)(lane & 15);
    unsigned node = (unsigned)(blockIdx.x * 16 + wv);   // always < NN (exact grid)
    int start = cursor[node];
    int deg = degI[node];
    int myIdx = 0;
    if (lane < deg) myIdx = csrSrc[(unsigned)(start + lane)];
    uint2 qs = H2[node * 16u + f];
    float di = dinv[node];
    float4 bb = bias4[f];
    float ax = 0.f, ay = 0.f, az = 0.f, aw = 0.f;
    float bx = 0.f, by = 0.f, bz = 0.f, bw = 0.f;
    uint2 qa[4];
#pragma unroll
    for (int r = 0; r < 4; ++r) {
        int e = r * 4 + g;
        unsigned s = (unsigned)__shfl(myIdx, e);
        qa[r] = make_uint2(0u, 0u);
        if (e < deg) qa[r] = H2[s * 16u + f];
    }
    if (deg <= 16) {
#pragma unroll
        for (int r = 0; r < 4; r += 2) {
            ax += blo(qa[r].x);     ay += bhi(qa[r].x);
            az += blo(qa[r].y);     aw += bhi(qa[r].y);
            bx += blo(qa[r + 1].x); by += bhi(qa[r + 1].x);
            bz += blo(qa[r + 1].y); bw += bhi(qa[r + 1].y);
        }
    } else {
        uint2 qb[4];
#pragma unroll
        for (int r = 0; r < 4; ++r) {
            int e = 16 + r * 4 + g;
            unsigned s = (unsigned)__shfl(myIdx, e);
            qb[r] = make_uint2(0u, 0u);
            if (e < deg) qb[r] = H2[s * 16u + f];
        }
#pragma unroll
        for (int r = 0; r < 4; r += 2) {
            ax += blo(qa[r].x);     ay += bhi(qa[r].x);
            az += blo(qa[r].y);     aw += bhi(qa[r].y);
            bx += blo(qa[r + 1].x); by += bhi(qa[r + 1].x);
            bz += blo(qa[r + 1].y); bw += bhi(qa[r + 1].y);
        }
#pragma unroll
        for (int r = 0; r < 4; r += 2) {
            ax += blo(qb[r].x);     ay += bhi(qb[r].x);
            az += blo(qb[r].y);     aw += bhi(qb[r].y);
            bx += blo(qb[r + 1].x); by += bhi(qb[r + 1].x);
            bz += blo(qb[r + 1].y); bw += bhi(qb[r + 1].y);
        }
        if (deg > 32) {
            int R2 = (deg + 3) >> 2;
            if (R2 > 16) R2 = 16;
            for (int r = 8; r < R2; ++r) {
                int e = r * 4 + g;
                unsigned s = (unsigned)__shfl(myIdx, e);
                uint2 qq = make_uint2(0u, 0u);
                if (e < deg) qq = H2[s * 16u + f];
                ax += blo(qq.x); ay += bhi(qq.x); az += blo(qq.y); aw += bhi(qq.y);
            }
            for (int ee = 64 + g; ee < deg; ee += 4) {
                uint2 qq = H2[(unsigned)csrSrc[(unsigned)(start + ee)] * 16u + f];
                ax += blo(qq.x); ay += bhi(qq.x); az += blo(qq.y); aw += bhi(qq.y);
            }
        }
    }
    ax += bx; ay += by; az += bz; aw += bw;
    ax += __shfl_xor(ax, 16); ay += __shfl_xor(ay, 16);
    az += __shfl_xor(az, 16); aw += __shfl_xor(aw, 16);
    ax += __shfl_xor(ax, 32); ay += __shfl_xor(ay, 32);
    az += __shfl_xor(az, 32); aw += __shfl_xor(aw, 32);
    float vx = fmaxf((ax + blo(qs.x)) * di + bb.x, 0.f);
    float vy = fmaxf((ay + bhi(qs.x)) * di + bb.y, 0.f);
    float vz = fmaxf((az + blo(qs.y)) * di + bb.z, 0.f);
    float vw = fmaxf((aw + bhi(qs.y)) * di + bb.w, 0.f);
    if (DOLN) {
        float s = vx + vy + vz + vw;
        s += __shfl_xor(s, 1); s += __shfl_xor(s, 2);
        s += __shfl_xor(s, 4); s += __shfl_xor(s, 8);
        float mu = s * (1.f / 64.f);
        vx -= mu; vy -= mu; vz -= mu; vw -= mu;
        float vs = vx * vx + vy * vy + vz * vz + vw * vw;
        vs += __shfl_xor(vs, 1); vs += __shfl_xor(vs, 2);
        vs += __shfl_xor(vs, 4); vs += __shfl_xor(vs, 8);
        float inv = rsqrtf(vs * (1.f / 64.f) + LN_EPS);
        float4 gg = g4[f];
        float4 tt = beta4[f];
        vx = vx * inv * gg.x + tt.x;
        vy = vy * inv * gg.y + tt.y;
        vz = vz * inv * gg.z + tt.z;
        vw = vw * inv * gg.w + tt.w;
    }
    // stage this node's row in LDS, exact packed-H bit layout (words 2f, 2f+1)
    if (g == 0) {
        sH[wv][2 * f] = bpack(vx, vy);
        sH[wv][2 * f + 1] = bpack(vz, vw);
    }
    __syncthreads();
    // ---- fused GEMM: 16 nodes x 64 @ W, waves 0..NT-1 (t = wv), direct
    // global writes from the MFMA accumulator (no sD, no second barrier).
    constexpr int NT = FINAL ? 3 : 4;
    if (wv < NT) {
        int q = lane >> 4, ln = lane & 15;
        short8 a0 = __builtin_bit_cast(short8, ((const uint4*)sH[ln])[q]);       // k = q*8..q*8+7
        short8 a1 = __builtin_bit_cast(short8, ((const uint4*)sH[ln])[4 + q]);   // k = 32+q*8..
        f32x4 acc = {0.f, 0.f, 0.f, 0.f};
        acc = __builtin_amdgcn_mfma_f32_16x16x32_bf16(
            a0, __builtin_bit_cast(short8, Wpk[(0 * NT + wv) * 64 + lane]), acc, 0, 0, 0);
        acc = __builtin_amdgcn_mfma_f32_16x16x32_bf16(
            a1, __builtin_bit_cast(short8, Wpk[(1 * NT + wv) * 64 + lane]), acc, 0, 0, 0);
        // D layout: lane 16q+ln holds rows q*4+r (r=reg), col = wv*16+ln
        if (FINAL) {
            int col = wv * 16 + ln;
#pragma unroll
            for (int r = 0; r < 4; ++r) {
                unsigned nd = (unsigned)(blockIdx.x * 16 + q * 4 + r);
                if (col < DOUT) outF[nd * (unsigned)DOUT + col] = acc[r] + bfv[col];
            }
        } else {
#pragma unroll
            for (int r = 0; r < 4; ++r) {
                unsigned nd = (unsigned)(blockIdx.x * 16 + q * 4 + r);
                float vv = acc[r] * dinv[nd];
                float lo = __shfl(vv, q * 16 + (ln & ~1));
                float hi = __shfl(vv, q * 16 + (ln | 1));
                if (!(ln & 1)) Hout[nd * 32u + wv * 8 + (ln >> 1)] = bpack(lo, hi);
            }
        }
    }
}

// ----------------------------------------------------------------
extern "C" void kernel_launch(void* const* d_in, const int* in_sizes, int n_in,
                              void* d_out, int out_size, void* d_ws, size_t ws_size,
                              hipStream_t stream) {
    const float* x    = (const float*)d_in[0];
    const int*   ei   = (const int*)d_in[1];
    const int*   srcI = ei;
    const int*   dstI = ei + EE;
    const float* W0   = (const float*)d_in[2];
    const float* b0   = (const float*)d_in[3];
    const float* W1   = (const float*)d_in[4];
    const float* b1   = (const float*)d_in[5];
    const float* W2   = (const float*)d_in[6];
    const float* b2   = (const float*)d_in[7];
    const float* ln0g = (const float*)d_in[8];
    const float* ln0b = (const float*)d_in[9];
    const float* ln1g = (const float*)d_in[10];
    const float* ln1b = (const float*)d_in[11];
    const float* mpW0 = (const float*)d_in[12];
    const float* mpb0 = (const float*)d_in[13];
    const float* mpW1 = (const float*)d_in[14];
    const float* mpb1 = (const float*)d_in[15];
    float* out = (float*)d_out;

    char* ws = (char*)d_ws;
    float*    dinv      = (float*)   (ws + 0);                      // 400 KB
    int*      degI      = (int*)     (ws + 512l * 1024);            // 400 KB
    int*      cursor    = (int*)     (ws + 1024l * 1024);           // 400 KB
    int*      bucketCur = (int*)     (ws + 1600l * 1024);
    uint4*    W0pk      = (uint4*)   (ws + 1792l * 1024);           // 16 KB
    uint4*    W1pk      = (uint4*)   (ws + 1824l * 1024);           // 8 KB
    uint4*    W2pk      = (uint4*)   (ws + 1856l * 1024);           // 8 KB
    uint4*    Wfpk      = (uint4*)   (ws + 1888l * 1024);           // 6 KB
    float*    bfv       = (float*)   (ws + 1920l * 1024);           // 192 B
    unsigned* bE        = (unsigned*)(ws + 2048l * 1024);           // 391*8192*4 = 12.8 MB
    int*      csrSrc    = (int*)     (ws + 15l * 1024 * 1024);      // 6.4 MB
    unsigned* bufA      = (unsigned*)(ws + 22l * 1024 * 1024);      // bf16 H' 12.8 MB
    unsigned* bufB      = (unsigned*)(ws + 36l * 1024 * 1024);      // bf16 H' ping-pong 12.8 MB

    const int aggBlocks  = NN / 16;            // 6250 exact
    const int gemmBlocks = (NN + 63) / 64;     // 1563

    hipMemsetAsync(bucketCur, 0, NBUCK * sizeof(int), stream);
    bucket_k<<<TBLK + 1, 1024, 0, stream>>>(srcI, dstI, bucketCur, bE,
                                            W0, W1, W2, mpW0, mpb0, mpW1, mpb1,
                                            W0pk, W1pk, W2pk, Wfpk, bfv);
    reorder2_k<<<NBUCK, 1024, 0, stream>>>(bucketCur, bE, csrSrc, degI, cursor, dinv);

    // layer 0 GEMM (f32 input)
    gemm0<<<gemmBlocks, 256, 0, stream>>>(x, W0pk, dinv, bufA);
    // conv0 finish (LN0) + fused GEMM W1
    aggf_k<1, 0><<<aggBlocks, 1024, 0, stream>>>(cursor, degI, csrSrc, dinv,
                                                 (const uint2*)bufA, (const float4*)b0,
                                                 (const float4*)ln0g, (const float4*)ln0b,
                                                 W1pk, bfv, bufB, out);
    // conv1 finish (LN1) + fused GEMM W2
    aggf_k<1, 0><<<aggBlocks, 1024, 0, stream>>>(cursor, degI, csrSrc, dinv,
                                                 (const uint2*)bufB, (const float4*)b1,
                                                 (const float4*)ln1g, (const float4*)ln1b,
                                                 W2pk, bfv, bufA, out);
    // conv2 finish (no LN) + fused head GEMM Wf + bf -> output
    aggf_k<0, 1><<<aggBlocks, 1024, 0, stream>>>(cursor, degI, csrSrc, dinv,
                                                 (const uint2*)bufA, (const float4*)b2,
                                                 (const float4*)ln0g, (const float4*)ln0b,
                                                 Wfpk, bfv, bufB, out);
}

// Round 18
// 303.639 us; speedup vs baseline: 1.1396x; 1.0615x over previous
//
#include <hip/hip_runtime.h>
#include <hip/hip_bf16.h>

#define NN 100000
#define EE 1600000
#define DOUT 40
#define LN_EPS 1e-5f
#define NBUCK 391  // buckets of 256 dst nodes
#define TILE 4096
#define TBLK 391   // ceil(EE/TILE)
#define BCAP 8192  // per-bucket capacity (expected 4092 +- 64)

typedef __attribute__((ext_vector_type(8))) short short8;   // 8 bf16 = 4 VGPRs
typedef __attribute__((ext_vector_type(4))) float f32x4;    // MFMA acc

// ---------------------------------------------------------------- bf16 helpers (RNE pack)
__device__ __forceinline__ float blo(unsigned u) { return __uint_as_float(u << 16); }
__device__ __forceinline__ float bhi(unsigned u) { return __uint_as_float(u & 0xffff0000u); }
__device__ __forceinline__ unsigned bpack(float lo, float hi) {
    unsigned a = __float_as_uint(lo);
    unsigned b = __float_as_uint(hi);
    a = (a + 0x7fffu + ((a >> 16) & 1u)) >> 16;
    b = (b + 0x7fffu + ((b >> 16) & 1u)) & 0xffff0000u;
    return (a & 0xffffu) | b;
}

// ---------------------------------------------------------------- bucket build (+ prep in last block)
__global__ __launch_bounds__(1024, 4) void bucket_k(
        const int* __restrict__ src, const int* __restrict__ dst,
        int* __restrict__ bucketCur, unsigned* __restrict__ bE,
        const float* __restrict__ W0, const float* __restrict__ W1,
        const float* __restrict__ W2,
        const float* __restrict__ mpW0, const float* __restrict__ mpb0,
        const float* __restrict__ mpW1, const float* __restrict__ mpb1,
        uint4* __restrict__ W0pk, uint4* __restrict__ W1pk,
        uint4* __restrict__ W2pk, uint4* __restrict__ Wfpk,
        float* __restrict__ bf) {
    __shared__ int cnt[8][NBUCK];
    __shared__ int basew[8][NBUCK];
    int tid = threadIdx.x;
    if (blockIdx.x == TBLK) {
        // ---------------- prep: fuse head linears + pre-pack all weights
        float* sWf = (float*)&basew[0][0];   // 12512 B >= 64*48*4 = 12288 B
        for (int i = tid; i < 64 * 48; i += 1024) {
            int k = i / 48, n = i % 48;
            float acc = 0.f;
            if (n < DOUT) {
                for (int j = 0; j < 64; ++j) acc = fmaf(mpW0[k * 64 + j], mpW1[j * DOUT + n], acc);
            }
            sWf[i] = acc;
        }
        for (int n = tid; n < 48; n += 1024) {
            float acc = 0.f;
            if (n < DOUT) {
                acc = mpb1[n];
                for (int j = 0; j < 64; ++j) acc = fmaf(mpb0[j], mpW1[j * DOUT + n], acc);
            }
            bf[n] = acc;
        }
        for (int i = tid; i < 1024; i += 1024) {
            int lane = i & 63, ct = i >> 6;
            int q = lane >> 4, ln = lane & 15;
            int c = ct >> 2, t = ct & 3;
            int row0 = c * 32 + q * 8, col = t * 16 + ln;
            uint4 u;
            u.x = bpack(W0[(row0 + 0) * 64 + col], W0[(row0 + 1) * 64 + col]);
            u.y = bpack(W0[(row0 + 2) * 64 + col], W0[(row0 + 3) * 64 + col]);
            u.z = bpack(W0[(row0 + 4) * 64 + col], W0[(row0 + 5) * 64 + col]);
            u.w = bpack(W0[(row0 + 6) * 64 + col], W0[(row0 + 7) * 64 + col]);
            W0pk[i] = u;
        }
        for (int i = tid; i < 512; i += 1024) {
            int lane = i & 63, ct = i >> 6;
            int q = lane >> 4, ln = lane & 15;
            int c = ct >> 2, t = ct & 3;
            int row0 = c * 32 + q * 8, col = t * 16 + ln;
            uint4 u;
            u.x = bpack(W1[(row0 + 0) * 64 + col], W1[(row0 + 1) * 64 + col]);
            u.y = bpack(W1[(row0 + 2) * 64 + col], W1[(row0 + 3) * 64 + col]);
            u.z = bpack(W1[(row0 + 4) * 64 + col], W1[(row0 + 5) * 64 + col]);
            u.w = bpack(W1[(row0 + 6) * 64 + col], W1[(row0 + 7) * 64 + col]);
            W1pk[i] = u;
            uint4 v;
            v.x = bpack(W2[(row0 + 0) * 64 + col], W2[(row0 + 1) * 64 + col]);
            v.y = bpack(W2[(row0 + 2) * 64 + col], W2[(row0 + 3) * 64 + col]);
            v.z = bpack(W2[(row0 + 4) * 64 + col], W2[(row0 + 5) * 64 + col]);
            v.w = bpack(W2[(row0 + 6) * 64 + col], W2[(row0 + 7) * 64 + col]);
            W2pk[i] = v;
        }
        __syncthreads();
        for (int i = tid; i < 384; i += 1024) {
            int lane = i & 63, ct = i >> 6;   // ct in 0..5
            int q = lane >> 4, ln = lane & 15;
            int c = ct / 3, t = ct % 3;
            int row0 = c * 32 + q * 8, col = t * 16 + ln;
            uint4 u;
            u.x = bpack(sWf[(row0 + 0) * 48 + col], sWf[(row0 + 1) * 48 + col]);
            u.y = bpack(sWf[(row0 + 2) * 48 + col], sWf[(row0 + 3) * 48 + col]);
            u.z = bpack(sWf[(row0 + 4) * 48 + col], sWf[(row0 + 5) * 48 + col]);
            u.w = bpack(sWf[(row0 + 6) * 48 + col], sWf[(row0 + 7) * 48 + col]);
            Wfpk[i] = u;
        }
        return;
    }
    int hv = tid >> 7;   // 0..7, two waves share one histogram row
    for (int i = tid; i < 8 * NBUCK; i += 1024) ((int*)cnt)[i] = 0;
    __syncthreads();
    const int4* dst4 = (const int4*)dst;
    const int4* src4 = (const int4*)src;
    long i4 = (long)blockIdx.x * 1024 + tid;   // TILE/4 = 1024
    int4 dv = make_int4(-1, -1, -1, -1);
    int4 sv = make_int4(0, 0, 0, 0);
    if (i4 < EE / 4) { dv = dst4[i4]; sv = src4[i4]; }
    int d[4] = {dv.x, dv.y, dv.z, dv.w};
    int s[4] = {sv.x, sv.y, sv.z, sv.w};
#pragma unroll
    for (int i = 0; i < 4; ++i) {
        if (d[i] >= 0) atomicAdd(&cnt[hv][d[i] >> 8], 1);
    }
    __syncthreads();
    for (int b = tid; b < NBUCK; b += 1024) {
        int c[8];
        int tot = 0;
#pragma unroll
        for (int w = 0; w < 8; ++w) { c[w] = cnt[w][b]; tot += c[w]; }
        int base = tot ? atomicAdd(&bucketCur[b], tot) : 0;
        int run = b * BCAP + base;
#pragma unroll
        for (int w = 0; w < 8; ++w) { basew[w][b] = run; run += c[w]; cnt[w][b] = 0; }
    }
    __syncthreads();
#pragma unroll
    for (int i = 0; i < 4; ++i) {
        if (d[i] >= 0) {
            int b = d[i] >> 8;
            int pos = basew[hv][b] + atomicAdd(&cnt[hv][b], 1);
            bE[pos] = (unsigned)s[i] | ((unsigned)(d[i] & 255) << 24);
        }
    }
}

// ---------------------------------------------------------------- bucket -> exact CSR + degI + cursor + dinv
__global__ __launch_bounds__(1024, 4) void reorder2_k(const int* __restrict__ bucketCur,
                                                      const unsigned* __restrict__ bE,
                                                      int* __restrict__ csrSrc,
                                                      int* __restrict__ degI,
                                                      int* __restrict__ cursor,
                                                      float* __restrict__ dinv) {
    __shared__ int sScan[512];
    __shared__ int sHist[256];
    __shared__ int sPre[256];
    __shared__ int sStart[256];
    int tid = threadIdx.x;
    int b = blockIdx.x;
    if (tid < 512) sScan[tid] = (tid < NBUCK) ? bucketCur[tid] : 0;
    __syncthreads();
    for (int off = 1; off < 512; off <<= 1) {
        int t = (tid >= off && tid < 512) ? sScan[tid - off] : 0;
        __syncthreads();
        if (tid < 512) sScan[tid] += t;
        __syncthreads();
    }
    int bbase = (b == 0) ? 0 : sScan[b - 1];   // LDS broadcast
    if (tid < 256) sHist[tid] = 0;
    __syncthreads();
    int start = b * BCAP;
    int ecnt = bucketCur[b];
    int nq = ecnt >> 2;
    const uint4* bE4 = (const uint4*)(bE + start);
    for (int i = tid; i < nq; i += 1024) {
        uint4 v = bE4[i];
        atomicAdd(&sHist[v.x >> 24], 1);
        atomicAdd(&sHist[v.y >> 24], 1);
        atomicAdd(&sHist[v.z >> 24], 1);
        atomicAdd(&sHist[v.w >> 24], 1);
    }
    for (int e = (nq << 2) + tid; e < ecnt; e += 1024) {
        atomicAdd(&sHist[bE[start + e] >> 24], 1);
    }
    __syncthreads();
    if (tid < 256) sPre[tid] = sHist[tid];
    __syncthreads();
    for (int off = 1; off < 256; off <<= 1) {
        int t = (tid >= off && tid < 256) ? sPre[tid - off] : 0;
        __syncthreads();
        if (tid < 256) sPre[tid] += t;
        __syncthreads();
    }
    if (tid < 256) {
        int h = sHist[tid];
        int excl = sPre[tid] - h;
        int st = bbase + excl;
        sStart[tid] = st;
        int nd = (b << 8) + tid;
        if (nd < NN) {
            degI[nd] = h;
            cursor[nd] = st;
            dinv[nd] = rsqrtf((float)h + 1.0f);
        }
    }
    __syncthreads();
    for (int i = tid; i < nq; i += 1024) {
        uint4 v = bE4[i];
        int p0 = atomicAdd(&sStart[v.x >> 24], 1);
        csrSrc[p0] = (int)(v.x & 0xFFFFFFu);
        int p1 = atomicAdd(&sStart[v.y >> 24], 1);
        csrSrc[p1] = (int)(v.y & 0xFFFFFFu);
        int p2 = atomicAdd(&sStart[v.z >> 24], 1);
        csrSrc[p2] = (int)(v.z & 0xFFFFFFu);
        int p3 = atomicAdd(&sStart[v.w >> 24], 1);
        csrSrc[p3] = (int)(v.w & 0xFFFFFFu);
    }
    for (int e = (nq << 2) + tid; e < ecnt; e += 1024) {
        unsigned v = bE[start + e];
        int pos = atomicAdd(&sStart[v >> 24], 1);
        csrSrc[pos] = (int)(v & 0xFFFFFFu);
    }
}

// ---------------------------------------------------------------- MFMA GEMM layer 0 (f32 input): H' = bf16((X@W0)*dinv)
__global__ __launch_bounds__(256, 4) void gemm0(const float* __restrict__ X,
                                                const uint4* __restrict__ Wpk,
                                                const float* __restrict__ dinv,
                                                unsigned* __restrict__ H) {
    __shared__ float sD[64 * 65];
    int tid = threadIdx.x;
    int wv = tid >> 6, lane = tid & 63;
    int q = lane >> 4, ln = lane & 15;
    int base = blockIdx.x * 64;
    int node = base + wv * 16 + ln;
    bool ok = node < NN;
    short8 afrag[4];
#pragma unroll
    for (int c = 0; c < 4; ++c) {
        float4 f0 = make_float4(0.f, 0.f, 0.f, 0.f);
        float4 f1 = make_float4(0.f, 0.f, 0.f, 0.f);
        if (ok) {
            const float4* xp = (const float4*)(X + (long)node * 128 + c * 32 + q * 8);
            f0 = xp[0];
            f1 = xp[1];
        }
        uint4 u;
        u.x = bpack(f0.x, f0.y);
        u.y = bpack(f0.z, f0.w);
        u.z = bpack(f1.x, f1.y);
        u.w = bpack(f1.z, f1.w);
        afrag[c] = __builtin_bit_cast(short8, u);
    }
#pragma unroll
    for (int t = 0; t < 4; ++t) {
        f32x4 acc = {0.f, 0.f, 0.f, 0.f};
#pragma unroll
        for (int c = 0; c < 4; ++c) {
            short8 bfrag = __builtin_bit_cast(short8, Wpk[(c * 4 + t) * 64 + lane]);
            acc = __builtin_amdgcn_mfma_f32_16x16x32_bf16(afrag[c], bfrag, acc, 0, 0, 0);
        }
#pragma unroll
        for (int r = 0; r < 4; ++r)
            sD[(wv * 16 + q * 4 + r) * 65 + t * 16 + ln] = acc[r];
    }
    __syncthreads();
    for (int i = tid; i < 64 * 32; i += 256) {
        int row = i >> 5, c2 = i & 31;
        int nd = base + row;
        if (nd < NN) {
            float di = dinv[nd];
            float lo = sD[row * 65 + c2 * 2] * di;
            float hi = sD[row * 65 + c2 * 2 + 1] * di;
            H[nd * 32 + c2] = bpack(lo, hi);
        }
    }
}

// ---------------------------------------------------------------- fused aggregate + relu (+LN) + NEXT-LAYER GEMM
// 256 threads = 4 waves = 4 nodes/block (agg_k's proven shape; 100000 =
// 25000*4 exact).  Round-15/17 lesson: a 16-wave barrier couples the
// gather to the block's slowest node (E[max of 16 Poisson(16)] ~ 28 edges
// vs mean 16) - that coupling, not the epilogue style, was the +13-20us.
// Here the barrier spans only 4 waves (E[max of 4] ~ 21).  Epilogue:
// stage 4 rows in sH, one barrier, each wave computes one t-tile of the
// same MFMAs (A rows ln&3; rows 4..15 duplicates, discarded - MfmaUtil
// was 0.5% so 4x MFMA issue is free) and writes directly from the
// accumulator.  All __shfl sources lie in the active lane set.
template <int DOLN, int FINAL>
__global__ __launch_bounds__(256, 4) void aggf_k(
        const int* __restrict__ cursor, const int* __restrict__ degI,
        const int* __restrict__ csrSrc, const float* __restrict__ dinv,
        const uint2* __restrict__ H2, const float4* __restrict__ bias4,
        const float4* __restrict__ g4, const float4* __restrict__ beta4,
        const uint4* __restrict__ Wpk, const float* __restrict__ bfv,
        unsigned* __restrict__ Hout, float* __restrict__ outF) {
    __shared__ __align__(16) unsigned sH[4][36];
    int tid = threadIdx.x;
    int wv = tid >> 6, lane = tid & 63;
    int g = lane >> 4;
    unsigned f = (unsigned)(lane & 15);
    unsigned node = (unsigned)(blockIdx.x * 4 + wv);   // always < NN (exact grid)
    int start = cursor[node];
    int deg = degI[node];
    int myIdx = 0;
    if (lane < deg) myIdx = csrSrc[(unsigned)(start + lane)];
    uint2 qs = H2[node * 16u + f];
    float di = dinv[node];
    float4 bb = bias4[f];
    float ax = 0.f, ay = 0.f, az = 0.f, aw = 0.f;
    float bx = 0.f, by = 0.f, bz = 0.f, bw = 0.f;
    uint2 qa[4];
#pragma unroll
    for (int r = 0; r < 4; ++r) {
        int e = r * 4 + g;
        unsigned s = (unsigned)__shfl(myIdx, e);
        qa[r] = make_uint2(0u, 0u);
        if (e < deg) qa[r] = H2[s * 16u + f];
    }
    if (deg <= 16) {
#pragma unroll
        for (int r = 0; r < 4; r += 2) {
            ax += blo(qa[r].x);     ay += bhi(qa[r].x);
            az += blo(qa[r].y);     aw += bhi(qa[r].y);
            bx += blo(qa[r + 1].x); by += bhi(qa[r + 1].x);
            bz += blo(qa[r + 1].y); bw += bhi(qa[r + 1].y);
        }
    } else {
        uint2 qb[4];
#pragma unroll
        for (int r = 0; r < 4; ++r) {
            int e = 16 + r * 4 + g;
            unsigned s = (unsigned)__shfl(myIdx, e);
            qb[r] = make_uint2(0u, 0u);
            if (e < deg) qb[r] = H2[s * 16u + f];
        }
#pragma unroll
        for (int r = 0; r < 4; r += 2) {
            ax += blo(qa[r].x);     ay += bhi(qa[r].x);
            az += blo(qa[r].y);     aw += bhi(qa[r].y);
            bx += blo(qa[r + 1].x); by += bhi(qa[r + 1].x);
            bz += blo(qa[r + 1].y); bw += bhi(qa[r + 1].y);
        }
#pragma unroll
        for (int r = 0; r < 4; r += 2) {
            ax += blo(qb[r].x);     ay += bhi(qb[r].x);
            az += blo(qb[r].y);     aw += bhi(qb[r].y);
            bx += blo(qb[r + 1].x); by += bhi(qb[r + 1].x);
            bz += blo(qb[r + 1].y); bw += bhi(qb[r + 1].y);
        }
        if (deg > 32) {
            int R2 = (deg + 3) >> 2;
            if (R2 > 16) R2 = 16;
            for (int r = 8; r < R2; ++r) {
                int e = r * 4 + g;
                unsigned s = (unsigned)__shfl(myIdx, e);
                uint2 qq = make_uint2(0u, 0u);
                if (e < deg) qq = H2[s * 16u + f];
                ax += blo(qq.x); ay += bhi(qq.x); az += blo(qq.y); aw += bhi(qq.y);
            }
            for (int ee = 64 + g; ee < deg; ee += 4) {
                uint2 qq = H2[(unsigned)csrSrc[(unsigned)(start + ee)] * 16u + f];
                ax += blo(qq.x); ay += bhi(qq.x); az += blo(qq.y); aw += bhi(qq.y);
            }
        }
    }
    ax += bx; ay += by; az += bz; aw += bw;
    ax += __shfl_xor(ax, 16); ay += __shfl_xor(ay, 16);
    az += __shfl_xor(az, 16); aw += __shfl_xor(aw, 16);
    ax += __shfl_xor(ax, 32); ay += __shfl_xor(ay, 32);
    az += __shfl_xor(az, 32); aw += __shfl_xor(aw, 32);
    float vx = fmaxf((ax + blo(qs.x)) * di + bb.x, 0.f);
    float vy = fmaxf((ay + bhi(qs.x)) * di + bb.y, 0.f);
    float vz = fmaxf((az + blo(qs.y)) * di + bb.z, 0.f);
    float vw = fmaxf((aw + bhi(qs.y)) * di + bb.w, 0.f);
    if (DOLN) {
        float s = vx + vy + vz + vw;
        s += __shfl_xor(s, 1); s += __shfl_xor(s, 2);
        s += __shfl_xor(s, 4); s += __shfl_xor(s, 8);
        float mu = s * (1.f / 64.f);
        vx -= mu; vy -= mu; vz -= mu; vw -= mu;
        float vs = vx * vx + vy * vy + vz * vz + vw * vw;
        vs += __shfl_xor(vs, 1); vs += __shfl_xor(vs, 2);
        vs += __shfl_xor(vs, 4); vs += __shfl_xor(vs, 8);
        float inv = rsqrtf(vs * (1.f / 64.f) + LN_EPS);
        float4 gg = g4[f];
        float4 tt = beta4[f];
        vx = vx * inv * gg.x + tt.x;
        vy = vy * inv * gg.y + tt.y;
        vz = vz * inv * gg.z + tt.z;
        vw = vw * inv * gg.w + tt.w;
    }
    // stage this node's row in LDS, exact packed-H bit layout (words 2f, 2f+1)
    if (g == 0) {
        sH[wv][2 * f] = bpack(vx, vy);
        sH[wv][2 * f + 1] = bpack(vz, vw);
    }
    __syncthreads();
    // ---- fused GEMM: 4 nodes x 64 @ W; wave wv = output tile t = wv.
    constexpr int NT = FINAL ? 3 : 4;
    if (wv < NT) {
        int q = lane >> 4, ln = lane & 15;
        // A row ln: rows 4..15 read duplicates of rows ln&3 (discarded)
        short8 a0 = __builtin_bit_cast(short8, ((const uint4*)sH[ln & 3])[q]);
        short8 a1 = __builtin_bit_cast(short8, ((const uint4*)sH[ln & 3])[4 + q]);
        f32x4 acc = {0.f, 0.f, 0.f, 0.f};
        acc = __builtin_amdgcn_mfma_f32_16x16x32_bf16(
            a0, __builtin_bit_cast(short8, Wpk[(0 * NT + wv) * 64 + lane]), acc, 0, 0, 0);
        acc = __builtin_amdgcn_mfma_f32_16x16x32_bf16(
            a1, __builtin_bit_cast(short8, Wpk[(1 * NT + wv) * 64 + lane]), acc, 0, 0, 0);
        // D: lane 16q+ln holds rows q*4+r, col wv*16+ln.  Valid rows 0..3 (q==0).
        if (FINAL) {
            int col = wv * 16 + ln;
#pragma unroll
            for (int r = 0; r < 4; ++r) {
                unsigned nd = (unsigned)(blockIdx.x * 4 + r);
                if (q == 0 && col < DOUT) outF[nd * (unsigned)DOUT + col] = acc[r] + bfv[col];
            }
        } else {
#pragma unroll
            for (int r = 0; r < 4; ++r) {
                unsigned nd = (unsigned)(blockIdx.x * 4 + r);
                float vv = acc[r] * dinv[nd];
                // pack column pairs: shfl executed by all lanes (sources in-set)
                float lo = __shfl(vv, (lane & 48) | (ln & ~1));
                float hi = __shfl(vv, (lane & 48) | ln | 1);
                if (q == 0 && !(ln & 1))
                    Hout[nd * 32u + wv * 8 + (ln >> 1)] = bpack(lo, hi);
            }
        }
    }
}

// ----------------------------------------------------------------
extern "C" void kernel_launch(void* const* d_in, const int* in_sizes, int n_in,
                              void* d_out, int out_size, void* d_ws, size_t ws_size,
                              hipStream_t stream) {
    const float* x    = (const float*)d_in[0];
    const int*   ei   = (const int*)d_in[1];
    const int*   srcI = ei;
    const int*   dstI = ei + EE;
    const float* W0   = (const float*)d_in[2];
    const float* b0   = (const float*)d_in[3];
    const float* W1   = (const float*)d_in[4];
    const float* b1   = (const float*)d_in[5];
    const float* W2   = (const float*)d_in[6];
    const float* b2   = (const float*)d_in[7];
    const float* ln0g = (const float*)d_in[8];
    const float* ln0b = (const float*)d_in[9];
    const float* ln1g = (const float*)d_in[10];
    const float* ln1b = (const float*)d_in[11];
    const float* mpW0 = (const float*)d_in[12];
    const float* mpb0 = (const float*)d_in[13];
    const float* mpW1 = (const float*)d_in[14];
    const float* mpb1 = (const float*)d_in[15];
    float* out = (float*)d_out;

    char* ws = (char*)d_ws;
    float*    dinv      = (float*)   (ws + 0);                      // 400 KB
    int*      degI      = (int*)     (ws + 512l * 1024);            // 400 KB
    int*      cursor    = (int*)     (ws + 1024l * 1024);           // 400 KB
    int*      bucketCur = (int*)     (ws + 1600l * 1024);
    uint4*    W0pk      = (uint4*)   (ws + 1792l * 1024);           // 16 KB
    uint4*    W1pk      = (uint4*)   (ws + 1824l * 1024);           // 8 KB
    uint4*    W2pk      = (uint4*)   (ws + 1856l * 1024);           // 8 KB
    uint4*    Wfpk      = (uint4*)   (ws + 1888l * 1024);           // 6 KB
    float*    bfv       = (float*)   (ws + 1920l * 1024);           // 192 B
    unsigned* bE        = (unsigned*)(ws + 2048l * 1024);           // 391*8192*4 = 12.8 MB
    int*      csrSrc    = (int*)     (ws + 15l * 1024 * 1024);      // 6.4 MB
    unsigned* bufA      = (unsigned*)(ws + 22l * 1024 * 1024);      // bf16 H' 12.8 MB
    unsigned* bufB      = (unsigned*)(ws + 36l * 1024 * 1024);      // bf16 H' ping-pong 12.8 MB

    const int aggBlocks  = NN / 4;             // 25000 exact
    const int gemmBlocks = (NN + 63) / 64;     // 1563

    hipMemsetAsync(bucketCur, 0, NBUCK * sizeof(int), stream);
    bucket_k<<<TBLK + 1, 1024, 0, stream>>>(srcI, dstI, bucketCur, bE,
                                            W0, W1, W2, mpW0, mpb0, mpW1, mpb1,
                                            W0pk, W1pk, W2pk, Wfpk, bfv);
    reorder2_k<<<NBUCK, 1024, 0, stream>>>(bucketCur, bE, csrSrc, degI, cursor, dinv);

    // layer 0 GEMM (f32 input)
    gemm0<<<gemmBlocks, 256, 0, stream>>>(x, W0pk, dinv, bufA);
    // conv0 finish (LN0) + fused GEMM W1
    aggf_k<1, 0><<<aggBlocks, 256, 0, stream>>>(cursor, degI, csrSrc, dinv,
                                                (const uint2*)bufA, (const float4*)b0,
                                                (const float4*)ln0g, (const float4*)ln0b,
                                                W1pk, bfv, bufB, out);
    // conv1 finish (LN1) + fused GEMM W2
    aggf_k<1, 0><<<aggBlocks, 256, 0, stream>>>(cursor, degI, csrSrc, dinv,
                                                (const uint2*)bufB, (const float4*)b1,
                                                (const float4*)ln1g, (const float4*)ln1b,
                                                W2pk, bfv, bufA, out);
    // conv2 finish (no LN) + fused head GEMM Wf + bf -> output
    aggf_k<0, 1><<<aggBlocks, 256, 0, stream>>>(cursor, degI, csrSrc, dinv,
                                                (const uint2*)bufA, (const float4*)b2,
                                                (const float4*)ln0g, (const float4*)ln0b,
                                                Wfpk, bfv, bufB, out);
}

// Round 19
// 301.698 us; speedup vs baseline: 1.1470x; 1.0064x over previous
//
#include <hip/hip_runtime.h>
#include <hip/hip_bf16.h>

#define NN 100000
#define EE 1600000
#define DOUT 40
#define LN_EPS 1e-5f
#define NBUCK 391  // buckets of 256 dst nodes
#define TILE 4096
#define TBLK 391   // ceil(EE/TILE)
#define BCAP 8192  // per-bucket capacity (expected 4092 +- 64)

typedef __attribute__((ext_vector_type(8))) short short8;   // 8 bf16 = 4 VGPRs
typedef __attribute__((ext_vector_type(4))) float f32x4;    // MFMA acc

// ---------------------------------------------------------------- bf16 helpers (RNE pack)
__device__ __forceinline__ float blo(unsigned u) { return __uint_as_float(u << 16); }
__device__ __forceinline__ float bhi(unsigned u) { return __uint_as_float(u & 0xffff0000u); }
__device__ __forceinline__ unsigned bpack(float lo, float hi) {
    unsigned a = __float_as_uint(lo);
    unsigned b = __float_as_uint(hi);
    a = (a + 0x7fffu + ((a >> 16) & 1u)) >> 16;
    b = (b + 0x7fffu + ((b >> 16) & 1u)) & 0xffff0000u;
    return (a & 0xffffu) | b;
}

// ---------------------------------------------------------------- bucket build (+ prep in last block)
__global__ __launch_bounds__(1024, 4) void bucket_k(
        const int* __restrict__ src, const int* __restrict__ dst,
        int* __restrict__ bucketCur, unsigned* __restrict__ bE,
        const float* __restrict__ W0, const float* __restrict__ W1,
        const float* __restrict__ W2,
        const float* __restrict__ mpW0, const float* __restrict__ mpb0,
        const float* __restrict__ mpW1, const float* __restrict__ mpb1,
        uint4* __restrict__ W0pk, uint4* __restrict__ W1pk,
        uint4* __restrict__ W2pk, uint4* __restrict__ Wfpk,
        float* __restrict__ bf) {
    __shared__ int cnt[8][NBUCK];
    __shared__ int basew[8][NBUCK];
    int tid = threadIdx.x;
    if (blockIdx.x == TBLK) {
        // ---------------- prep: fuse head linears + pre-pack all weights
        float* sWf = (float*)&basew[0][0];   // 12512 B >= 64*48*4 = 12288 B
        for (int i = tid; i < 64 * 48; i += 1024) {
            int k = i / 48, n = i % 48;
            float acc = 0.f;
            if (n < DOUT) {
                for (int j = 0; j < 64; ++j) acc = fmaf(mpW0[k * 64 + j], mpW1[j * DOUT + n], acc);
            }
            sWf[i] = acc;
        }
        for (int n = tid; n < 48; n += 1024) {
            float acc = 0.f;
            if (n < DOUT) {
                acc = mpb1[n];
                for (int j = 0; j < 64; ++j) acc = fmaf(mpb0[j], mpW1[j * DOUT + n], acc);
            }
            bf[n] = acc;
        }
        for (int i = tid; i < 1024; i += 1024) {
            int lane = i & 63, ct = i >> 6;
            int q = lane >> 4, ln = lane & 15;
            int c = ct >> 2, t = ct & 3;
            int row0 = c * 32 + q * 8, col = t * 16 + ln;
            uint4 u;
            u.x = bpack(W0[(row0 + 0) * 64 + col], W0[(row0 + 1) * 64 + col]);
            u.y = bpack(W0[(row0 + 2) * 64 + col], W0[(row0 + 3) * 64 + col]);
            u.z = bpack(W0[(row0 + 4) * 64 + col], W0[(row0 + 5) * 64 + col]);
            u.w = bpack(W0[(row0 + 6) * 64 + col], W0[(row0 + 7) * 64 + col]);
            W0pk[i] = u;
        }
        for (int i = tid; i < 512; i += 1024) {
            int lane = i & 63, ct = i >> 6;
            int q = lane >> 4, ln = lane & 15;
            int c = ct >> 2, t = ct & 3;
            int row0 = c * 32 + q * 8, col = t * 16 + ln;
            uint4 u;
            u.x = bpack(W1[(row0 + 0) * 64 + col], W1[(row0 + 1) * 64 + col]);
            u.y = bpack(W1[(row0 + 2) * 64 + col], W1[(row0 + 3) * 64 + col]);
            u.z = bpack(W1[(row0 + 4) * 64 + col], W1[(row0 + 5) * 64 + col]);
            u.w = bpack(W1[(row0 + 6) * 64 + col], W1[(row0 + 7) * 64 + col]);
            W1pk[i] = u;
            uint4 v;
            v.x = bpack(W2[(row0 + 0) * 64 + col], W2[(row0 + 1) * 64 + col]);
            v.y = bpack(W2[(row0 + 2) * 64 + col], W2[(row0 + 3) * 64 + col]);
            v.z = bpack(W2[(row0 + 4) * 64 + col], W2[(row0 + 5) * 64 + col]);
            v.w = bpack(W2[(row0 + 6) * 64 + col], W2[(row0 + 7) * 64 + col]);
            W2pk[i] = v;
        }
        __syncthreads();
        for (int i = tid; i < 384; i += 1024) {
            int lane = i & 63, ct = i >> 6;   // ct in 0..5
            int q = lane >> 4, ln = lane & 15;
            int c = ct / 3, t = ct % 3;
            int row0 = c * 32 + q * 8, col = t * 16 + ln;
            uint4 u;
            u.x = bpack(sWf[(row0 + 0) * 48 + col], sWf[(row0 + 1) * 48 + col]);
            u.y = bpack(sWf[(row0 + 2) * 48 + col], sWf[(row0 + 3) * 48 + col]);
            u.z = bpack(sWf[(row0 + 4) * 48 + col], sWf[(row0 + 5) * 48 + col]);
            u.w = bpack(sWf[(row0 + 6) * 48 + col], sWf[(row0 + 7) * 48 + col]);
            Wfpk[i] = u;
        }
        return;
    }
    int hv = tid >> 7;   // 0..7, two waves share one histogram row
    for (int i = tid; i < 8 * NBUCK; i += 1024) ((int*)cnt)[i] = 0;
    __syncthreads();
    const int4* dst4 = (const int4*)dst;
    const int4* src4 = (const int4*)src;
    long i4 = (long)blockIdx.x * 1024 + tid;   // TILE/4 = 1024
    int4 dv = make_int4(-1, -1, -1, -1);
    int4 sv = make_int4(0, 0, 0, 0);
    if (i4 < EE / 4) { dv = dst4[i4]; sv = src4[i4]; }
    int d[4] = {dv.x, dv.y, dv.z, dv.w};
    int s[4] = {sv.x, sv.y, sv.z, sv.w};
#pragma unroll
    for (int i = 0; i < 4; ++i) {
        if (d[i] >= 0) atomicAdd(&cnt[hv][d[i] >> 8], 1);
    }
    __syncthreads();
    for (int b = tid; b < NBUCK; b += 1024) {
        int c[8];
        int tot = 0;
#pragma unroll
        for (int w = 0; w < 8; ++w) { c[w] = cnt[w][b]; tot += c[w]; }
        int base = tot ? atomicAdd(&bucketCur[b], tot) : 0;
        int run = b * BCAP + base;
#pragma unroll
        for (int w = 0; w < 8; ++w) { basew[w][b] = run; run += c[w]; cnt[w][b] = 0; }
    }
    __syncthreads();
#pragma unroll
    for (int i = 0; i < 4; ++i) {
        if (d[i] >= 0) {
            int b = d[i] >> 8;
            int pos = basew[hv][b] + atomicAdd(&cnt[hv][b], 1);
            bE[pos] = (unsigned)s[i] | ((unsigned)(d[i] & 255) << 24);
        }
    }
}

// ---------------------------------------------------------------- bucket -> exact CSR + degI + cursor + dinv
__global__ __launch_bounds__(1024, 4) void reorder2_k(const int* __restrict__ bucketCur,
                                                      const unsigned* __restrict__ bE,
                                                      int* __restrict__ csrSrc,
                                                      int* __restrict__ degI,
                                                      int* __restrict__ cursor,
                                                      float* __restrict__ dinv) {
    __shared__ int sScan[512];
    __shared__ int sHist[256];
    __shared__ int sPre[256];
    __shared__ int sStart[256];
    int tid = threadIdx.x;
    int b = blockIdx.x;
    if (tid < 512) sScan[tid] = (tid < NBUCK) ? bucketCur[tid] : 0;
    __syncthreads();
    for (int off = 1; off < 512; off <<= 1) {
        int t = (tid >= off && tid < 512) ? sScan[tid - off] : 0;
        __syncthreads();
        if (tid < 512) sScan[tid] += t;
        __syncthreads();
    }
    int bbase = (b == 0) ? 0 : sScan[b - 1];   // LDS broadcast
    if (tid < 256) sHist[tid] = 0;
    __syncthreads();
    int start = b * BCAP;
    int ecnt = bucketCur[b];
    int nq = ecnt >> 2;
    const uint4* bE4 = (const uint4*)(bE + start);
    for (int i = tid; i < nq; i += 1024) {
        uint4 v = bE4[i];
        atomicAdd(&sHist[v.x >> 24], 1);
        atomicAdd(&sHist[v.y >> 24], 1);
        atomicAdd(&sHist[v.z >> 24], 1);
        atomicAdd(&sHist[v.w >> 24], 1);
    }
    for (int e = (nq << 2) + tid; e < ecnt; e += 1024) {
        atomicAdd(&sHist[bE[start + e] >> 24], 1);
    }
    __syncthreads();
    if (tid < 256) sPre[tid] = sHist[tid];
    __syncthreads();
    for (int off = 1; off < 256; off <<= 1) {
        int t = (tid >= off && tid < 256) ? sPre[tid - off] : 0;
        __syncthreads();
        if (tid < 256) sPre[tid] += t;
        __syncthreads();
    }
    if (tid < 256) {
        int h = sHist[tid];
        int excl = sPre[tid] - h;
        int st = bbase + excl;
        sStart[tid] = st;
        int nd = (b << 8) + tid;
        if (nd < NN) {
            degI[nd] = h;
            cursor[nd] = st;
            dinv[nd] = rsqrtf((float)h + 1.0f);
        }
    }
    __syncthreads();
    for (int i = tid; i < nq; i += 1024) {
        uint4 v = bE4[i];
        int p0 = atomicAdd(&sStart[v.x >> 24], 1);
        csrSrc[p0] = (int)(v.x & 0xFFFFFFu);
        int p1 = atomicAdd(&sStart[v.y >> 24], 1);
        csrSrc[p1] = (int)(v.y & 0xFFFFFFu);
        int p2 = atomicAdd(&sStart[v.z >> 24], 1);
        csrSrc[p2] = (int)(v.z & 0xFFFFFFu);
        int p3 = atomicAdd(&sStart[v.w >> 24], 1);
        csrSrc[p3] = (int)(v.w & 0xFFFFFFu);
    }
    for (int e = (nq << 2) + tid; e < ecnt; e += 1024) {
        unsigned v = bE[start + e];
        int pos = atomicAdd(&sStart[v >> 24], 1);
        csrSrc[pos] = (int)(v & 0xFFFFFFu);
    }
}

// ---------------------------------------------------------------- MFMA GEMM layer 0 (f32 input): H' = bf16((X@W0)*dinv)
// Operand-swapped MFMA (D = Wfrag x xfrag): lane (q,ln) holds 4 CONSECUTIVE
// features q*4+r (tile t) of node ln -> direct uint2 packed-bf16 stores.
// No LDS, no barrier, no output staging loop.
__global__ __launch_bounds__(256, 4) void gemm0(const float* __restrict__ X,
                                                const uint4* __restrict__ Wpk,
                                                const float* __restrict__ dinv,
                                                unsigned* __restrict__ H) {
    int tid = threadIdx.x;
    int wv = tid >> 6, lane = tid & 63;
    int q = lane >> 4, ln = lane & 15;
    int base = blockIdx.x * 64;
    int node = base + wv * 16 + ln;
    bool ok = node < NN;
    short8 afrag[4];
#pragma unroll
    for (int c = 0; c < 4; ++c) {
        float4 f0 = make_float4(0.f, 0.f, 0.f, 0.f);
        float4 f1 = make_float4(0.f, 0.f, 0.f, 0.f);
        if (ok) {
            const float4* xp = (const float4*)(X + (long)node * 128 + c * 32 + q * 8);
            f0 = xp[0];
            f1 = xp[1];
        }
        uint4 u;
        u.x = bpack(f0.x, f0.y);
        u.y = bpack(f0.z, f0.w);
        u.z = bpack(f1.x, f1.y);
        u.w = bpack(f1.z, f1.w);
        afrag[c] = __builtin_bit_cast(short8, u);
    }
    float dn = ok ? dinv[node] : 0.f;
#pragma unroll
    for (int t = 0; t < 4; ++t) {
        f32x4 acc = {0.f, 0.f, 0.f, 0.f};
#pragma unroll
        for (int c = 0; c < 4; ++c) {
            short8 wfrag = __builtin_bit_cast(short8, Wpk[(c * 4 + t) * 64 + lane]);
            acc = __builtin_amdgcn_mfma_f32_16x16x32_bf16(wfrag, afrag[c], acc, 0, 0, 0);
        }
        if (ok) {
            uint2 w2 = make_uint2(bpack(acc[0] * dn, acc[1] * dn),
                                  bpack(acc[2] * dn, acc[3] * dn));
            *(uint2*)(H + (unsigned)node * 32u + t * 8 + q * 2) = w2;
        }
    }
}

// ---------------------------------------------------------------- fused aggregate + relu (+LN) + NEXT-LAYER GEMM
// 256 threads = 4 waves = 4 nodes/block.  Gather: one wave per node
// (round-9/10 structure, __shfl under full exec).  Epilogue: stage 4 rows
// in sH, one 4-wave barrier, wave wv computes tile t=wv with OPERAND-
// SWAPPED MFMA (D = Wfrag x hfrag): lane (q,ln) then holds 4 consecutive
// output features of node ln -> one uint2 (or float4) store per lane,
// ZERO epilogue shuffles (round-18's shfl-pack loop was the epilogue's
// VALU cost).  Bit-identical dot products.
template <int DOLN, int FINAL>
__global__ __launch_bounds__(256, 4) void aggf_k(
        const int* __restrict__ cursor, const int* __restrict__ degI,
        const int* __restrict__ csrSrc, const float* __restrict__ dinv,
        const uint2* __restrict__ H2, const float4* __restrict__ bias4,
        const float4* __restrict__ g4, const float4* __restrict__ beta4,
        const uint4* __restrict__ Wpk, const float* __restrict__ bfv,
        unsigned* __restrict__ Hout, float* __restrict__ outF) {
    __shared__ __align__(16) unsigned sH[4][36];
    int tid = threadIdx.x;
    int wv = tid >> 6, lane = tid & 63;
    int g = lane >> 4;
    unsigned f = (unsigned)(lane & 15);
    unsigned node = (unsigned)(blockIdx.x * 4 + wv);   // always < NN (exact grid)
    int start = cursor[node];
    int deg = degI[node];
    int myIdx = 0;
    if (lane < deg) myIdx = csrSrc[(unsigned)(start + lane)];
    uint2 qs = H2[node * 16u + f];
    float di = dinv[node];
    float4 bb = bias4[f];
    float ax = 0.f, ay = 0.f, az = 0.f, aw = 0.f;
    float bx = 0.f, by = 0.f, bz = 0.f, bw = 0.f;
    uint2 qa[4];
#pragma unroll
    for (int r = 0; r < 4; ++r) {
        int e = r * 4 + g;
        unsigned s = (unsigned)__shfl(myIdx, e);
        qa[r] = make_uint2(0u, 0u);
        if (e < deg) qa[r] = H2[s * 16u + f];
    }
    if (deg <= 16) {
#pragma unroll
        for (int r = 0; r < 4; r += 2) {
            ax += blo(qa[r].x);     ay += bhi(qa[r].x);
            az += blo(qa[r].y);     aw += bhi(qa[r].y);
            bx += blo(qa[r + 1].x); by += bhi(qa[r + 1].x);
            bz += blo(qa[r + 1].y); bw += bhi(qa[r + 1].y);
        }
    } else {
        uint2 qb[4];
#pragma unroll
        for (int r = 0; r < 4; ++r) {
            int e = 16 + r * 4 + g;
            unsigned s = (unsigned)__shfl(myIdx, e);
            qb[r] = make_uint2(0u, 0u);
            if (e < deg) qb[r] = H2[s * 16u + f];
        }
#pragma unroll
        for (int r = 0; r < 4; r += 2) {
            ax += blo(qa[r].x);     ay += bhi(qa[r].x);
            az += blo(qa[r].y);     aw += bhi(qa[r].y);
            bx += blo(qa[r + 1].x); by += bhi(qa[r + 1].x);
            bz += blo(qa[r + 1].y); bw += bhi(qa[r + 1].y);
        }
#pragma unroll
        for (int r = 0; r < 4; r += 2) {
            ax += blo(qb[r].x);     ay += bhi(qb[r].x);
            az += blo(qb[r].y);     aw += bhi(qb[r].y);
            bx += blo(qb[r + 1].x); by += bhi(qb[r + 1].x);
            bz += blo(qb[r + 1].y); bw += bhi(qb[r + 1].y);
        }
        if (deg > 32) {
            int R2 = (deg + 3) >> 2;
            if (R2 > 16) R2 = 16;
            for (int r = 8; r < R2; ++r) {
                int e = r * 4 + g;
                unsigned s = (unsigned)__shfl(myIdx, e);
                uint2 qq = make_uint2(0u, 0u);
                if (e < deg) qq = H2[s * 16u + f];
                ax += blo(qq.x); ay += bhi(qq.x); az += blo(qq.y); aw += bhi(qq.y);
            }
            for (int ee = 64 + g; ee < deg; ee += 4) {
                uint2 qq = H2[(unsigned)csrSrc[(unsigned)(start + ee)] * 16u + f];
                ax += blo(qq.x); ay += bhi(qq.x); az += blo(qq.y); aw += bhi(qq.y);
            }
        }
    }
    ax += bx; ay += by; az += bz; aw += bw;
    ax += __shfl_xor(ax, 16); ay += __shfl_xor(ay, 16);
    az += __shfl_xor(az, 16); aw += __shfl_xor(aw, 16);
    ax += __shfl_xor(ax, 32); ay += __shfl_xor(ay, 32);
    az += __shfl_xor(az, 32); aw += __shfl_xor(aw, 32);
    float vx = fmaxf((ax + blo(qs.x)) * di + bb.x, 0.f);
    float vy = fmaxf((ay + bhi(qs.x)) * di + bb.y, 0.f);
    float vz = fmaxf((az + blo(qs.y)) * di + bb.z, 0.f);
    float vw = fmaxf((aw + bhi(qs.y)) * di + bb.w, 0.f);
    if (DOLN) {
        float s = vx + vy + vz + vw;
        s += __shfl_xor(s, 1); s += __shfl_xor(s, 2);
        s += __shfl_xor(s, 4); s += __shfl_xor(s, 8);
        float mu = s * (1.f / 64.f);
        vx -= mu; vy -= mu; vz -= mu; vw -= mu;
        float vs = vx * vx + vy * vy + vz * vz + vw * vw;
        vs += __shfl_xor(vs, 1); vs += __shfl_xor(vs, 2);
        vs += __shfl_xor(vs, 4); vs += __shfl_xor(vs, 8);
        float inv = rsqrtf(vs * (1.f / 64.f) + LN_EPS);
        float4 gg = g4[f];
        float4 tt = beta4[f];
        vx = vx * inv * gg.x + tt.x;
        vy = vy * inv * gg.y + tt.y;
        vz = vz * inv * gg.z + tt.z;
        vw = vw * inv * gg.w + tt.w;
    }
    // stage this node's row in LDS, exact packed-H bit layout (words 2f, 2f+1)
    if (g == 0) {
        sH[wv][2 * f] = bpack(vx, vy);
        sH[wv][2 * f + 1] = bpack(vz, vw);
    }
    __syncthreads();
    // ---- fused GEMM, operand-swapped: wave wv computes tile t = wv.
    constexpr int NT = FINAL ? 3 : 4;
    if (wv < NT) {
        int q = lane >> 4, ln = lane & 15;
        // B operand: h rows; cols (nodes) valid for ln < 4
        short8 h0 = __builtin_bit_cast(short8, ((const uint4*)sH[ln & 3])[q]);
        short8 h1 = __builtin_bit_cast(short8, ((const uint4*)sH[ln & 3])[4 + q]);
        f32x4 acc = {0.f, 0.f, 0.f, 0.f};
        acc = __builtin_amdgcn_mfma_f32_16x16x32_bf16(
            __builtin_bit_cast(short8, Wpk[(0 * NT + wv) * 64 + lane]), h0, acc, 0, 0, 0);
        acc = __builtin_amdgcn_mfma_f32_16x16x32_bf16(
            __builtin_bit_cast(short8, Wpk[(1 * NT + wv) * 64 + lane]), h1, acc, 0, 0, 0);
        // D: lane (q,ln) holds output features wv*16+q*4+r of node ln (ln<4 valid)
        if (lane < 4 || (ln < 4)) { /* keep flow simple; real guard below */ }
        if ((lane & 15) < 4) {
            unsigned nd = (unsigned)(blockIdx.x * 4 + ln);
            if (FINAL) {
                int col0 = wv * 16 + q * 4;
                if (col0 < DOUT) {
                    float4 o = make_float4(acc[0] + bfv[col0], acc[1] + bfv[col0 + 1],
                                           acc[2] + bfv[col0 + 2], acc[3] + bfv[col0 + 3]);
                    *(float4*)(outF + nd * (unsigned)DOUT + col0) = o;
                }
            } else {
                float dn = dinv[nd];
                uint2 w2 = make_uint2(bpack(acc[0] * dn, acc[1] * dn),
                                      bpack(acc[2] * dn, acc[3] * dn));
                *(uint2*)(Hout + nd * 32u + wv * 8 + q * 2) = w2;
            }
        }
    }
}

// ----------------------------------------------------------------
extern "C" void kernel_launch(void* const* d_in, const int* in_sizes, int n_in,
                              void* d_out, int out_size, void* d_ws, size_t ws_size,
                              hipStream_t stream) {
    const float* x    = (const float*)d_in[0];
    const int*   ei   = (const int*)d_in[1];
    const int*   srcI = ei;
    const int*   dstI = ei + EE;
    const float* W0   = (const float*)d_in[2];
    const float* b0   = (const float*)d_in[3];
    const float* W1   = (const float*)d_in[4];
    const float* b1   = (const float*)d_in[5];
    const float* W2   = (const float*)d_in[6];
    const float* b2   = (const float*)d_in[7];
    const float* ln0g = (const float*)d_in[8];
    const float* ln0b = (const float*)d_in[9];
    const float* ln1g = (const float*)d_in[10];
    const float* ln1b = (const float*)d_in[11];
    const float* mpW0 = (const float*)d_in[12];
    const float* mpb0 = (const float*)d_in[13];
    const float* mpW1 = (const float*)d_in[14];
    const float* mpb1 = (const float*)d_in[15];
    float* out = (float*)d_out;

    char* ws = (char*)d_ws;
    float*    dinv      = (float*)   (ws + 0);                      // 400 KB
    int*      degI      = (int*)     (ws + 512l * 1024);            // 400 KB
    int*      cursor    = (int*)     (ws + 1024l * 1024);           // 400 KB
    int*      bucketCur = (int*)     (ws + 1600l * 1024);
    uint4*    W0pk      = (uint4*)   (ws + 1792l * 1024);           // 16 KB
    uint4*    W1pk      = (uint4*)   (ws + 1824l * 1024);           // 8 KB
    uint4*    W2pk      = (uint4*)   (ws + 1856l * 1024);           // 8 KB
    uint4*    Wfpk      = (uint4*)   (ws + 1888l * 1024);           // 6 KB
    float*    bfv       = (float*)   (ws + 1920l * 1024);           // 192 B
    unsigned* bE        = (unsigned*)(ws + 2048l * 1024);           // 391*8192*4 = 12.8 MB
    int*      csrSrc    = (int*)     (ws + 15l * 1024 * 1024);      // 6.4 MB
    unsigned* bufA      = (unsigned*)(ws + 22l * 1024 * 1024);      // bf16 H' 12.8 MB
    unsigned* bufB      = (unsigned*)(ws + 36l * 1024 * 1024);      // bf16 H' ping-pong 12.8 MB

    const int aggBlocks  = NN / 4;             // 25000 exact
    const int gemmBlocks = (NN + 63) / 64;     // 1563

    hipMemsetAsync(bucketCur, 0, NBUCK * sizeof(int), stream);
    bucket_k<<<TBLK + 1, 1024, 0, stream>>>(srcI, dstI, bucketCur, bE,
                                            W0, W1, W2, mpW0, mpb0, mpW1, mpb1,
                                            W0pk, W1pk, W2pk, Wfpk, bfv);
    reorder2_k<<<NBUCK, 1024, 0, stream>>>(bucketCur, bE, csrSrc, degI, cursor, dinv);

    // layer 0 GEMM (f32 input)
    gemm0<<<gemmBlocks, 256, 0, stream>>>(x, W0pk, dinv, bufA);
    // conv0 finish (LN0) + fused GEMM W1
    aggf_k<1, 0><<<aggBlocks, 256, 0, stream>>>(cursor, degI, csrSrc, dinv,
                                                (const uint2*)bufA, (const float4*)b0,
                                                (const float4*)ln0g, (const float4*)ln0b,
                                                W1pk, bfv, bufB, out);
    // conv1 finish (LN1) + fused GEMM W2
    aggf_k<1, 0><<<aggBlocks, 256, 0, stream>>>(cursor, degI, csrSrc, dinv,
                                                (const uint2*)bufB, (const float4*)b1,
                                                (const float4*)ln1g, (const float4*)ln1b,
                                                W2pk, bfv, bufA, out);
    // conv2 finish (no LN) + fused head GEMM Wf + bf -> output
    aggf_k<0, 1><<<aggBlocks, 256, 0, stream>>>(cursor, degI, csrSrc, dinv,
                                                (const uint2*)bufA, (const float4*)b2,
                                                (const float4*)ln0g, (const float4*)ln0b,
                                                Wfpk, bfv, bufB, out);
}